// Round 12
// baseline (256.774 us; speedup 1.0000x reference)
//
#include <hip/hip_runtime.h>

#define NV   50000
#define NEV  10000
#define NNZV 600000
#define DIM  128

#define NBKE 157    // edge buckets: e>>6  (64 keys each)
#define NBKV 196    // vertex buckets: v>>8 (256 keys each)
#define NCB  293    // count blocks (2048 items each)
#define CH2  2048   // fused fill chunk
#define SCAP 7680

// workspace layout (float offsets) — total 3,401,920 floats = 13.6 MB (proven)
#define BPACK_OFF 0        // 16384: bf16 256x128 packed [C1;C3] (32768 ushorts)
#define WP_OFF    24576    // 16384: W'' = W1^T @ C2, f32 [k][o]
#define BA_OFF    40960    // 256: bA[0..128), b1C2[128..256)
#define A_OFF     41216    // 50048: per-vertex alpha sum
#define B_OFF     91264    // 10048: per-edge alpha sum
#define T_OFF     101312   // 1280000: f32 T; also C2tmp during prep
#define XEBF_OFF  1381312  // 640000 floats: bf16 Ye (1.28M ushort)
#define BCNTE_OFF 2021312  // int 256
#define BOFFE_OFF 2021568  // int 256
#define BCNTV_OFF 2021824  // int 256
#define BOFFV_OFF 2022080  // int 256
#define OFFV_OFF  2101376  // int 50016: exact-key CSR offsets (vertices)
#define CURE_OFF  2041344  // int (bcurE uses first 157)
#define CURV_OFF  2151392  // int (bcurV uses first 196)
#define PV_OFF    2201920  // int2 600000: (v<<14|e, alpha) grouped by vertex
// d_out timeline: Xbf (bf16 X, front 12.8MB) + PE pairs (int2 at float 3.2M) are
// written early, consumed by edge_sort_reduce, then gemm_pq overwrites ALL of
// d_out with R rows; vertex_fused does wave-local RMW of its own row.
#define PE_OUT_FLOAT_OFF 3200000

typedef __attribute__((ext_vector_type(8))) short bf16x8;
typedef __attribute__((ext_vector_type(4))) float f32x4;

__device__ __forceinline__ unsigned short f2bf(float x){
  unsigned u = __float_as_uint(x);
  u += 0x7fffu + ((u >> 16) & 1u);     // round-to-nearest-even
  return (unsigned short)(u >> 16);
}
__device__ __forceinline__ float bf2f(unsigned short h){
  return __uint_as_float((unsigned)h << 16);
}

// ---------------- prep1: pack [C1;C3], C2tmp, bA; blocks 385-388 zero counts ----------------
__global__ __launch_bounds__(128) void prep1(
        const float* __restrict__ W2w, const float* __restrict__ W2b,
        const float* __restrict__ Ww, float* __restrict__ ws){
  int b = blockIdx.x, o = threadIdx.x;
  if (b < 256){
    float s;
    if (b < 128){            // C1[k=b][o] = 0.5*sum_m Ww[o][m]*W2w[m][b]
      float acc = 0.f;
      for (int m = 0; m < 128; ++m) acc += Ww[o*128 + m] * W2w[m*256 + b];
      s = 0.5f * acc;
    } else {                 // C3[k=b-128][o] = 0.5*Ww[o][b-128]
      s = 0.5f * Ww[o*128 + (b - 128)];
    }
    int ks = b >> 5, g = (b >> 3) & 3, j = b & 7;
    int ct = o >> 4, lo = o & 15;
    unsigned short* Bp = (unsigned short*)(ws + BPACK_OFF);
    Bp[((size_t)((ks*8 + ct)*64 + g*16 + lo))*8 + j] = f2bf(s);
  } else if (b < 384){       // C2tmp[m][o]
    int m = b - 256;
    float acc = 0.f;
    for (int j = 0; j < 128; ++j) acc += Ww[o*128 + j] * W2w[j*256 + 128 + m];
    ws[T_OFF + m*128 + o] = 0.5f * acc;
  } else if (b == 384){      // bA
    float acc = 0.f;
    for (int m = 0; m < 128; ++m) acc += Ww[o*128 + m] * W2b[m];
    ws[BA_OFF + o] = 0.5f * acc;
  } else {                   // zero the 1024-int bcnt/bOff block
    int* z = (int*)(ws + BCNTE_OFF);
    int base = (b - 385)*256;
    z[base + o] = 0; z[base + 128 + o] = 0;
  }
}

// ---------------- prep2: W'' = W1^T @ C2tmp; b1C2 ----------------
__global__ __launch_bounds__(128) void prep2(
        const float* __restrict__ W1w, const float* __restrict__ W1b,
        float* __restrict__ ws){
  int b = blockIdx.x, o = threadIdx.x;
  const float* C2t = ws + T_OFF;
  if (b < 128){
    float acc = 0.f;
    for (int m = 0; m < 128; ++m) acc += W1w[m*128 + b] * C2t[m*128 + o];
    ws[WP_OFF + b*128 + o] = acc;
  } else {
    float acc = 0.f;
    for (int m = 0; m < 128; ++m) acc += W1b[m] * C2t[m*128 + o];
    ws[BA_OFF + 128 + o] = acc;
  }
}

// ---------------- merged: bucket histogram (blocks <NCB) + X->bf16 (rest) ----------------
__global__ __launch_bounds__(256) void count_tobf16(
        const int* __restrict__ vertex, const int* __restrict__ edges,
        const float* __restrict__ X,
        int* __restrict__ bcntE, int* __restrict__ bcntV,
        unsigned short* __restrict__ Xbf){
  int b = blockIdx.x, t = threadIdx.x;
  __shared__ int hE[256], hV[256];
  if (b < NCB){
    hE[t] = 0; hV[t] = 0;
    __syncthreads();
    int i0 = b * 2048;
    #pragma unroll
    for (int r = 0; r < 8; ++r){
      int i = i0 + r*256 + t;
      if (i < NNZV){
        atomicAdd(&hE[edges[i]  >> 6], 1);
        atomicAdd(&hV[vertex[i] >> 8], 1);
      }
    }
    __syncthreads();
    if (hE[t]) atomicAdd(bcntE + t, hE[t]);
    if (hV[t]) atomicAdd(bcntV + t, hV[t]);
  } else {
    int i = (b - NCB)*256 + t;
    if (i < NV*DIM/8){
      float4 v0 = ((const float4*)X)[(size_t)i*2];
      float4 v1 = ((const float4*)X)[(size_t)i*2 + 1];
      ushort4 h0, h1;
      h0.x=f2bf(v0.x); h0.y=f2bf(v0.y); h0.z=f2bf(v0.z); h0.w=f2bf(v0.w);
      h1.x=f2bf(v1.x); h1.y=f2bf(v1.y); h1.z=f2bf(v1.z); h1.w=f2bf(v1.w);
      ((ushort4*)Xbf)[(size_t)i*2]     = h0;
      ((ushort4*)Xbf)[(size_t)i*2 + 1] = h1;
    }
  }
}

// ---------------- tiny: scan bucket counts, init cursors, set tail offs ----------------
__global__ __launch_bounds__(256) void scan_buckets(
        const int* __restrict__ bcntE, const int* __restrict__ bcntV,
        int* __restrict__ bOffE, int* __restrict__ bOffV,
        int* __restrict__ bcurE, int* __restrict__ bcurV,
        int* __restrict__ offV){
  __shared__ int s[256];
  int t = threadIdx.x;
  int c = (t < NBKE) ? bcntE[t] : 0;
  s[t] = c; __syncthreads();
  for (int d = 1; d < 256; d <<= 1){
    int x = (t >= d) ? s[t-d] : 0;
    __syncthreads(); s[t] += x; __syncthreads();
  }
  if (t < NBKE){ bOffE[t] = s[t] - c; bcurE[t] = s[t] - c; }
  if (t == 0) bOffE[NBKE] = NNZV;
  __syncthreads();
  int c2 = (t < NBKV) ? bcntV[t] : 0;
  s[t] = c2; __syncthreads();
  for (int d = 1; d < 256; d <<= 1){
    int x = (t >= d) ? s[t-d] : 0;
    __syncthreads(); s[t] += x; __syncthreads();
  }
  if (t < NBKV){ bOffV[t] = s[t] - c2; bcurV[t] = s[t] - c2; }
  if (t == 0){ bOffV[NBKV] = NNZV; offV[NV] = NNZV; }
}

// ---------------- fused binning: one pass produces PE and PV ----------------
__global__ __launch_bounds__(256) void fill_binned2(
        const int* __restrict__ vertex, const int* __restrict__ edges,
        const float* __restrict__ alpha,
        int* __restrict__ bcurE, int* __restrict__ bcurV,
        int2* __restrict__ PE, int2* __restrict__ PV){
  __shared__ int histE[256], lofsE[256], gbaseE[256], posE[256];
  __shared__ int histV[256], lofsV[256], gbaseV[256], posV[256];
  __shared__ int ss[256];
  __shared__ int2 stgE[CH2], stgV[CH2];
  int t = threadIdx.x;
  int i0 = blockIdx.x * CH2;
  histE[t] = 0; histV[t] = 0;
  __syncthreads();
  int pkE[8], pkV[8], pa[8];
  #pragma unroll
  for (int r = 0; r < 8; ++r){
    int i = i0 + r*256 + t;
    int pe = -1, pv = -1, ab = 0;
    if (i < NNZV){
      int v = vertex[i], e = edges[i];
      ab = __float_as_int(alpha[i]);
      pe = (e << 16) | v;              // pe>>22 == e>>6
      pv = (v << 14) | e;              // pv>>22 == v>>8
      atomicAdd(&histE[pe >> 22], 1);
      atomicAdd(&histV[pv >> 22], 1);
    }
    pkE[r] = pe; pkV[r] = pv; pa[r] = ab;
  }
  __syncthreads();
  int cE = histE[t];
  ss[t] = cE; __syncthreads();
  for (int d = 1; d < 256; d <<= 1){
    int x = (t >= d) ? ss[t-d] : 0;
    __syncthreads(); ss[t] += x; __syncthreads();
  }
  lofsE[t] = ss[t] - cE; posE[t] = ss[t] - cE;
  __syncthreads();
  int cV = histV[t];
  ss[t] = cV; __syncthreads();
  for (int d = 1; d < 256; d <<= 1){
    int x = (t >= d) ? ss[t-d] : 0;
    __syncthreads(); ss[t] += x; __syncthreads();
  }
  lofsV[t] = ss[t] - cV; posV[t] = ss[t] - cV;
  __syncthreads();
  #pragma unroll
  for (int r = 0; r < 8; ++r){
    if (pkE[r] != -1){
      int p = atomicAdd(&posE[pkE[r] >> 22], 1);
      stgE[p] = make_int2(pkE[r], pa[r]);
      int q = atomicAdd(&posV[pkV[r] >> 22], 1);
      stgV[q] = make_int2(pkV[r], pa[r]);
    }
  }
  __syncthreads();
  {
    int cnt = histE[t];
    gbaseE[t] = cnt ? atomicAdd(&bcurE[t], cnt) : 0;
    int cnt2 = histV[t];
    gbaseV[t] = cnt2 ? atomicAdd(&bcurV[t], cnt2) : 0;
  }
  __syncthreads();
  int total = min(CH2, NNZV - i0);
  for (int s = t; s < total; s += 256){
    int lo = 0, hi = NBKE - 1;
    while (lo < hi){ int mid = (lo + hi + 1) >> 1; if (lofsE[mid] <= s) lo = mid; else hi = mid - 1; }
    PE[gbaseE[lo] + (s - lofsE[lo])] = stgE[s];
    lo = 0; hi = NBKV - 1;
    while (lo < hi){ int mid = (lo + hi + 1) >> 1; if (lofsV[mid] <= s) lo = mid; else hi = mid - 1; }
    PV[gbaseV[lo] + (s - lofsV[lo])] = stgV[s];
  }
}

// ---------------- fused: in-LDS sort of edge bucket + per-edge reduce ----------------
// T[e] = sum a*Xbf[v], B[e] = sum a.  No sorted-PE writeback, no offE.
__global__ __launch_bounds__(256) void edge_sort_reduce(
        const unsigned short* __restrict__ Xbf,
        const int2* __restrict__ PE, const int* __restrict__ bOffE,
        float* __restrict__ T, float* __restrict__ Bsum){
  int b = blockIdx.x, t = threadIdx.x;
  int k0 = b * 64;
  int r0 = bOffE[b], r1 = bOffE[b+1];
  int m = r1 - r0;
  __shared__ int hist[64], ssc[64], rnk[64];
  __shared__ int2 srt[SCAP];
  if (t < 64) hist[t] = 0;
  __syncthreads();
  bool inLds = (m <= SCAP);
  int px[30], py[30];
  if (inLds){
    #pragma unroll
    for (int r = 0; r < 30; ++r){
      int s = r*256 + t;
      int x = -1, y = 0;
      if (s < m){
        int2 p = PE[r0 + s];
        x = p.x; y = p.y;
        atomicAdd(&hist[(x >> 16) - k0], 1);
      }
      px[r] = x; py[r] = y;
    }
  } else {                           // statistically never: histogram from global
    for (int s = t; s < m; s += 256)
      atomicAdd(&hist[(PE[r0 + s].x >> 16) - k0], 1);
  }
  __syncthreads();
  if (t < 64) ssc[t] = hist[t];
  __syncthreads();
  for (int d = 1; d < 64; d <<= 1){
    int x = (t >= d && t < 64) ? ssc[t-d] : 0;
    __syncthreads();
    if (t < 64) ssc[t] += x;
    __syncthreads();
  }
  if (t < 64) rnk[t] = ssc[t] - hist[t];
  __syncthreads();
  if (inLds){
    #pragma unroll
    for (int r = 0; r < 30; ++r){
      if (px[r] != -1){
        int p = atomicAdd(&rnk[(px[r] >> 16) - k0], 1);
        srt[p] = make_int2(px[r], py[r]);
      }
    }
  }
  __syncthreads();
  // per-edge alpha sums (wave 0)
  if (t < 64){
    int e = k0 + t;
    if (e < NEV){
      float sa = 0.f;
      if (inLds){
        int s0 = ssc[t] - hist[t], s1 = ssc[t];
        for (int s = s0; s < s1; ++s) sa += __int_as_float(srt[s].y);
      } else {
        for (int s = 0; s < m; ++s){
          int2 p = PE[r0 + s];
          if ((p.x >> 16) == e) sa += __int_as_float(p.y);
        }
      }
      Bsum[e] = sa;
    }
  }
  // reduce: wave w handles local edges w, w+4, ...
  int w = t >> 6, l = t & 63;
  for (int le = w; le < 64; le += 4){
    int e = k0 + le;
    if (e >= NEV) break;
    float acc0 = 0.f, acc1 = 0.f;
    if (inLds){
      int s0 = ssc[le] - hist[le], s1 = ssc[le];
      int j = s0;
      for (; j + 4 <= s1; j += 4){
        int2 p0 = srt[j], p1 = srt[j+1], p2 = srt[j+2], p3 = srt[j+3];
        int v0 = (p0.x & 0xFFFF) << 7, v1 = (p1.x & 0xFFFF) << 7;
        int v2 = (p2.x & 0xFFFF) << 7, v3 = (p3.x & 0xFFFF) << 7;
        float x00 = bf2f(Xbf[v0 + l]),      x01 = bf2f(Xbf[v0 + 64 + l]);
        float x10 = bf2f(Xbf[v1 + l]),      x11 = bf2f(Xbf[v1 + 64 + l]);
        float x20 = bf2f(Xbf[v2 + l]),      x21 = bf2f(Xbf[v2 + 64 + l]);
        float x30 = bf2f(Xbf[v3 + l]),      x31 = bf2f(Xbf[v3 + 64 + l]);
        float a0 = __int_as_float(p0.y), a1 = __int_as_float(p1.y);
        float a2 = __int_as_float(p2.y), a3 = __int_as_float(p3.y);
        acc0 += a0*x00 + a1*x10 + a2*x20 + a3*x30;
        acc1 += a0*x01 + a1*x11 + a2*x21 + a3*x31;
      }
      for (; j < s1; ++j){
        int2 p = srt[j];
        int v = (p.x & 0xFFFF) << 7;
        float a = __int_as_float(p.y);
        acc0 += a * bf2f(Xbf[v + l]);
        acc1 += a * bf2f(Xbf[v + 64 + l]);
      }
    } else {                         // statistically never: filtered scan
      for (int s = 0; s < m; ++s){
        int2 p = PE[r0 + s];
        if ((p.x >> 16) == e){
          int v = (p.x & 0xFFFF) << 7;
          float a = __int_as_float(p.y);
          acc0 += a * bf2f(Xbf[v + l]);
          acc1 += a * bf2f(Xbf[v + 64 + l]);
        }
      }
    }
    size_t o = (size_t)e * DIM;
    T[o + l]      = acc0;
    T[o + 64 + l] = acc1;
  }
}

// ---------------- V-side: in-bucket counting sort + offV + A sums ----------------
__global__ __launch_bounds__(256) void sort_bucketV(
        int2* __restrict__ pairs, const int* __restrict__ bOff,
        int* __restrict__ off, float* __restrict__ sums,
        int2* __restrict__ bounce){
  const int kpb = 256, shift = 14, nkeys = NV;
  int b = blockIdx.x, t = threadIdx.x;
  int k0 = b * kpb;
  int r0 = bOff[b], r1 = bOff[b+1];
  int m = r1 - r0;
  __shared__ int hist[256], rnk[256], ssc[256];
  __shared__ int2 srt[SCAP];
  hist[t] = 0;
  __syncthreads();
  int px[30], py[30];
  #pragma unroll
  for (int r = 0; r < 30; ++r){
    int s = r*256 + t;
    int x = -1, y = 0;
    if (s < m && m <= SCAP){
      int2 p = pairs[r0 + s];
      x = p.x; y = p.y;
      atomicAdd(&hist[(x >> shift) - k0], 1);
    }
    px[r] = x; py[r] = y;
  }
  if (m > SCAP){
    for (int s = t; s < m; s += 256){
      int2 p = pairs[r0 + s];
      bounce[s] = p;
      atomicAdd(&hist[(p.x >> shift) - k0], 1);
    }
  }
  __syncthreads();
  int c = hist[t];
  ssc[t] = c; __syncthreads();
  for (int d = 1; d < 256; d <<= 1){
    int x = (t >= d) ? ssc[t-d] : 0;
    __syncthreads(); ssc[t] += x; __syncthreads();
  }
  rnk[t] = ssc[t] - c;
  {
    int k = k0 + t;
    if (k < nkeys) off[k] = r0 + ssc[t] - c;
  }
  __syncthreads();
  if (m <= SCAP){
    #pragma unroll
    for (int r = 0; r < 30; ++r){
      if (px[r] >= 0){
        int p = atomicAdd(&rnk[(px[r] >> shift) - k0], 1);
        srt[p] = make_int2(px[r], py[r]);
      }
    }
    __syncthreads();
    for (int s = t; s < m; s += 256) pairs[r0 + s] = srt[s];
    {
      int k = k0 + t;
      if (k < nkeys){
        float sa = 0.f;
        int s0 = ssc[t] - hist[t], s1 = ssc[t];
        for (int s = s0; s < s1; ++s) sa += __int_as_float(srt[s].y);
        sums[k] = sa;
      }
    }
  } else {
    __syncthreads();
    for (int s = t; s < m; s += 256){
      int2 p = bounce[s];
      int q = atomicAdd(&rnk[(p.x >> shift) - k0], 1);
      pairs[r0 + q] = p;
    }
    __syncthreads();
    {
      int k = k0 + t;
      if (k < nkeys){
        float sa = 0.f;
        int s0 = ssc[t] - hist[t], s1 = ssc[t];
        for (int s = s0; s < s1; ++s) sa += __int_as_float(pairs[r0 + s].y);
        sums[k] = sa;
      }
    }
  }
}

// ---------------- Ye = T @ W'' + B*b1C2  (writes bf16 XEBF) ----------------
__global__ __launch_bounds__(256) void gemm_ye(float* __restrict__ ws){
  __shared__ float Y[32][136];
  const float* T   = ws + T_OFF;
  const float* WP  = ws + WP_OFF;
  const float* Bs  = ws + B_OFF;
  const float* b1p = ws + BA_OFF + 128;
  unsigned short* Ye = (unsigned short*)(ws + XEBF_OFF);
  int n0 = blockIdx.x * 32;
  int tid = threadIdx.x;
  {
    int lr = tid >> 3, lj = tid & 7;
    int gn = n0 + lr; if (gn >= NEV) gn = NEV - 1;
    const float* src = T + (size_t)gn*DIM + lj*16;
    #pragma unroll
    for (int q = 0; q < 4; ++q)
      *(float4*)(&Y[lr][lj*16 + q*4]) = *(const float4*)(src + q*4);
  }
  __syncthreads();
  int rq = tid >> 5, cq = tid & 31;
  float acc[4][4];
  #pragma unroll
  for (int u=0;u<4;++u){ acc[u][0]=0;acc[u][1]=0;acc[u][2]=0;acc[u][3]=0; }
  const float* Crow = WP + cq*4;
  #pragma unroll 4
  for (int k = 0; k < 128; ++k){
    float4 c = *(const float4*)(Crow + (size_t)k*128);
    #pragma unroll
    for (int u = 0; u < 4; ++u){
      float y = Y[rq*4 + u][k];
      acc[u][0] += y*c.x; acc[u][1] += y*c.y; acc[u][2] += y*c.z; acc[u][3] += y*c.w;
    }
  }
  float4 b1v = *(const float4*)(b1p + cq*4);
  #pragma unroll
  for (int u = 0; u < 4; ++u){
    int e = n0 + rq*4 + u;
    if (e < NEV){
      float Bv = Bs[e];
      ushort4 h;
      h.x = f2bf(acc[u][0] + Bv*b1v.x); h.y = f2bf(acc[u][1] + Bv*b1v.y);
      h.z = f2bf(acc[u][2] + Bv*b1v.z); h.w = f2bf(acc[u][3] + Bv*b1v.w);
      *(ushort4*)(Ye + (size_t)e*DIM + cq*4) = h;
    }
  }
}

// ---------------- R = [Av*X | X0] @ [C1;C3] + Av*bA + Wb  (writes d_out rows) ----------------
#define LDS_STRIDE 264   // shorts per row: 256 + 8 pad

__global__ __launch_bounds__(256) void gemm_pq(
        const float* __restrict__ X, const float* __restrict__ X0,
        const float* __restrict__ Wb, const float* __restrict__ ws,
        float* __restrict__ R){
  __shared__ unsigned short At[64 * LDS_STRIDE];
  __shared__ float ArS[64];
  const float* Aa = ws + A_OFF;
  const float* bA = ws + BA_OFF;
  const unsigned short* Bpack = (const unsigned short*)(ws + BPACK_OFF);
  int r0 = blockIdx.x * 64;
  int t = threadIdx.x;
  if (t < 64){
    int gn = r0 + t; if (gn >= NV) gn = NV - 1;
    ArS[t] = Aa[gn];
  }
  __syncthreads();
  #pragma unroll
  for (int seg = 0; seg < 2; ++seg){
    const float* src = (seg == 0) ? X : X0;
    #pragma unroll
    for (int i = 0; i < 8; ++i){
      int idx = t + i*256;
      int row = idx >> 5;
      int c4  = idx & 31;
      int gn = r0 + row; if (gn >= NV) gn = NV - 1;
      float4 v = *(const float4*)(src + (size_t)gn*DIM + c4*4);
      if (seg == 0){
        float Ar = ArS[row];
        v.x *= Ar; v.y *= Ar; v.z *= Ar; v.w *= Ar;
      }
      ushort4 h;
      h.x = f2bf(v.x); h.y = f2bf(v.y); h.z = f2bf(v.z); h.w = f2bf(v.w);
      *(ushort4*)(&At[row*LDS_STRIDE + seg*128 + c4*4]) = h;
    }
  }
  __syncthreads();

  int w = t >> 6, l = t & 63;
  int m0 = w * 16;
  int lr = l & 15, lg = l >> 4;
  f32x4 acc[8];
  #pragma unroll
  for (int ct = 0; ct < 8; ++ct) acc[ct] = (f32x4){0.f,0.f,0.f,0.f};

  const unsigned short* arow = &At[(m0 + lr)*LDS_STRIDE + lg*8];
  #pragma unroll
  for (int ks = 0; ks < 8; ++ks){
    bf16x8 af = *(const bf16x8*)(arow + ks*32);
    const bf16x8* bp = (const bf16x8*)(Bpack) + (size_t)ks*8*64 + l;
    #pragma unroll
    for (int ct = 0; ct < 8; ++ct){
      bf16x8 bf = bp[ct*64];
      acc[ct] = __builtin_amdgcn_mfma_f32_16x16x32_bf16(af, bf, acc[ct], 0, 0, 0);
    }
  }

  #pragma unroll
  for (int ct = 0; ct < 8; ++ct){
    int o = ct*16 + lr;
    float ba = bA[o], wb = Wb[o];
    #pragma unroll
    for (int r = 0; r < 4; ++r){
      int lrow = m0 + lg*4 + r;
      int row = r0 + lrow;
      if (row < NV){
        float Av = ArS[lrow];
        R[(size_t)row*DIM + o] = acc[ct][r] + Av*ba + wb;
      }
    }
  }
}

// ---------------- wave-per-vertex: out[v] += sum a*Ye[e]  (barrier-free) ----------------
__global__ __launch_bounds__(256) void vertex_fused(
        const unsigned short* __restrict__ Ye, const int* __restrict__ offV,
        const int2* __restrict__ PV, float* __restrict__ out){
  int w = threadIdx.x >> 6, l = threadIdx.x & 63;
  int v = blockIdx.x*4 + w;
  int s0 = offV[v], s1 = offV[v+1];
  float acc0 = 0.f, acc1 = 0.f;
  int j = s0;
  for (; j + 4 <= s1; j += 4){
    int2 p0 = PV[j], p1 = PV[j+1], p2 = PV[j+2], p3 = PV[j+3];
    int e0 = (p0.x & 0x3FFF) << 7, e1 = (p1.x & 0x3FFF) << 7;
    int e2 = (p2.x & 0x3FFF) << 7, e3 = (p3.x & 0x3FFF) << 7;
    float y00 = bf2f(Ye[e0 + l]),      y01 = bf2f(Ye[e0 + 64 + l]);
    float y10 = bf2f(Ye[e1 + l]),      y11 = bf2f(Ye[e1 + 64 + l]);
    float y20 = bf2f(Ye[e2 + l]),      y21 = bf2f(Ye[e2 + 64 + l]);
    float y30 = bf2f(Ye[e3 + l]),      y31 = bf2f(Ye[e3 + 64 + l]);
    float a0 = __int_as_float(p0.y), a1 = __int_as_float(p1.y);
    float a2 = __int_as_float(p2.y), a3 = __int_as_float(p3.y);
    acc0 += a0*y00 + a1*y10 + a2*y20 + a3*y30;
    acc1 += a0*y01 + a1*y11 + a2*y21 + a3*y31;
  }
  for (; j < s1; ++j){
    int2 p = PV[j];
    int e = (p.x & 0x3FFF) << 7;
    float a = __int_as_float(p.y);
    acc0 += a * bf2f(Ye[e + l]);
    acc1 += a * bf2f(Ye[e + 64 + l]);
  }
  size_t o = (size_t)v * DIM;
  out[o + l]      += acc0;   // R already there; same thread, same address
  out[o + 64 + l] += acc1;
}

extern "C" void kernel_launch(void* const* d_in, const int* in_sizes, int n_in,
                              void* d_out, int out_size, void* d_ws, size_t ws_size,
                              hipStream_t stream){
  const float* X    = (const float*)d_in[0];
  const int*  vertex= (const int*)  d_in[1];
  const int*  edges = (const int*)  d_in[2];
  const float* X0   = (const float*)d_in[3];
  const float* alpha= (const float*)d_in[4];
  const float* W1w  = (const float*)d_in[5];
  const float* W1b  = (const float*)d_in[6];
  const float* W2w  = (const float*)d_in[7];
  const float* W2b  = (const float*)d_in[8];
  const float* Ww   = (const float*)d_in[9];
  const float* Wb   = (const float*)d_in[10];
  float* out = (float*)d_out;
  float* ws  = (float*)d_ws;

  int* bcntE = (int*)(ws + BCNTE_OFF);
  int* bOffE = (int*)(ws + BOFFE_OFF);
  int* bcntV = (int*)(ws + BCNTV_OFF);
  int* bOffV = (int*)(ws + BOFFV_OFF);
  int* bcurE = (int*)(ws + CURE_OFF);
  int* offV  = (int*)(ws + OFFV_OFF);
  int* bcurV = (int*)(ws + CURV_OFF);
  int2* PV   = (int2*)(ws + PV_OFF);
  int2* PE   = (int2*)(out + PE_OUT_FLOAT_OFF);
  int2* bounce = (int2*)(ws + T_OFF);
  unsigned short* Xbf = (unsigned short*)out;           // front 12.8 MB of d_out
  unsigned short* Ye  = (unsigned short*)(ws + XEBF_OFF);

  prep1          <<<389, 128, 0, stream>>>(W2w, W2b, Ww, ws);
  prep2          <<<129, 128, 0, stream>>>(W1w, W1b, ws);
  count_tobf16   <<<NCB + (NV*DIM/8 + 255)/256, 256, 0, stream>>>(vertex, edges, X,
                                                                  bcntE, bcntV, Xbf);
  scan_buckets   <<<1, 256, 0, stream>>>(bcntE, bcntV, bOffE, bOffV, bcurE, bcurV, offV);
  fill_binned2   <<<(NNZV + CH2 - 1)/CH2, 256, 0, stream>>>(vertex, edges, alpha,
                                                            bcurE, bcurV, PE, PV);
  edge_sort_reduce<<<NBKE, 256, 0, stream>>>(Xbf, PE, bOffE, ws + T_OFF, ws + B_OFF);
  gemm_ye        <<<(NEV + 31)/32, 256, 0, stream>>>(ws);
  sort_bucketV   <<<NBKV, 256, 0, stream>>>(PV, bOffV, offV, ws + A_OFF, bounce);
  gemm_pq        <<<(NV + 63)/64, 256, 0, stream>>>(X, X0, Wb, ws, out);
  vertex_fused   <<<NV/4, 256, 0, stream>>>(Ye, offV, PV, out);
}

// Round 13
// 181.442 us; speedup vs baseline: 1.4152x; 1.4152x over previous
//
#include <hip/hip_runtime.h>

#define NV   50000
#define NEV  10000
#define NNZV 600000
#define DIM  128

#define NBKE 157    // edge buckets: e>>6  (64 keys each)
#define NBKV 196    // vertex buckets: v>>8 (256 keys each)
#define NCB  293    // count blocks (2048 items each)
#define CH2  2048   // fused fill chunk
#define SCAP 7680

// workspace layout (float offsets) — total 3,401,920 floats = 13.6 MB (proven)
#define BPACK_OFF 0        // 16384: bf16 256x128 packed [C1;C3] (32768 ushorts)
#define WP_OFF    24576    // 16384: W'' = W1^T @ C2, f32 [k][o]
#define BA_OFF    40960    // 256: bA[0..128), b1C2[128..256)
#define A_OFF     41216    // 50048: per-vertex alpha sum
#define B_OFF     91264    // 10048: per-edge alpha sum
#define T_OFF     101312   // 1280000: f32 T; also C2tmp during prep + int2 bounce
#define XEBF_OFF  1381312  // 640000 floats: bf16 Ye (1.28M ushort)
#define BCNTE_OFF 2021312  // int 256
#define BOFFE_OFF 2021568  // int 256
#define BCNTV_OFF 2021824  // int 256
#define BOFFV_OFF 2022080  // int 256
#define OFFE_OFF  2031328  // int 10016: exact-key CSR offsets (edges)
#define CURE_OFF  2041344  // int (bcurE uses first 157)
#define OFFV_OFF  2101376  // int 50016: exact-key CSR offsets (vertices)
#define CURV_OFF  2151392  // int (bcurV uses first 196)
#define PV_OFF    2201920  // int2 600000: (v<<14|e, alpha) grouped by vertex
// d_out timeline: Xbf (bf16 X, front 12.8MB) + PE pairs (int2 at float 3.2M) are
// written early, consumed by edge_reduce, then gemm_pq overwrites ALL of d_out
// with R rows; vertex_fused does wave-local RMW of its own row.
#define PE_OUT_FLOAT_OFF 3200000

typedef __attribute__((ext_vector_type(8))) short bf16x8;
typedef __attribute__((ext_vector_type(4))) float f32x4;

__device__ __forceinline__ unsigned short f2bf(float x){
  unsigned u = __float_as_uint(x);
  u += 0x7fffu + ((u >> 16) & 1u);     // round-to-nearest-even
  return (unsigned short)(u >> 16);
}
__device__ __forceinline__ float bf2f(unsigned short h){
  return __uint_as_float((unsigned)h << 16);
}

// ---------------- prep1: pack [C1;C3], C2tmp, bA; blocks 385-388 zero counts ----------------
__global__ __launch_bounds__(128) void prep1(
        const float* __restrict__ W2w, const float* __restrict__ W2b,
        const float* __restrict__ Ww, float* __restrict__ ws){
  int b = blockIdx.x, o = threadIdx.x;
  if (b < 256){
    float s;
    if (b < 128){            // C1[k=b][o] = 0.5*sum_m Ww[o][m]*W2w[m][b]
      float acc = 0.f;
      for (int m = 0; m < 128; ++m) acc += Ww[o*128 + m] * W2w[m*256 + b];
      s = 0.5f * acc;
    } else {                 // C3[k=b-128][o] = 0.5*Ww[o][b-128]
      s = 0.5f * Ww[o*128 + (b - 128)];
    }
    int ks = b >> 5, g = (b >> 3) & 3, j = b & 7;
    int ct = o >> 4, lo = o & 15;
    unsigned short* Bp = (unsigned short*)(ws + BPACK_OFF);
    Bp[((size_t)((ks*8 + ct)*64 + g*16 + lo))*8 + j] = f2bf(s);
  } else if (b < 384){       // C2tmp[m][o]
    int m = b - 256;
    float acc = 0.f;
    for (int j = 0; j < 128; ++j) acc += Ww[o*128 + j] * W2w[j*256 + 128 + m];
    ws[T_OFF + m*128 + o] = 0.5f * acc;
  } else if (b == 384){      // bA
    float acc = 0.f;
    for (int m = 0; m < 128; ++m) acc += Ww[o*128 + m] * W2b[m];
    ws[BA_OFF + o] = 0.5f * acc;
  } else {                   // zero the 1024-int bcnt/bOff block
    int* z = (int*)(ws + BCNTE_OFF);
    int base = (b - 385)*256;
    z[base + o] = 0; z[base + 128 + o] = 0;
  }
}

// ---------------- prep2: W'' = W1^T @ C2tmp; b1C2 ----------------
__global__ __launch_bounds__(128) void prep2(
        const float* __restrict__ W1w, const float* __restrict__ W1b,
        float* __restrict__ ws){
  int b = blockIdx.x, o = threadIdx.x;
  const float* C2t = ws + T_OFF;
  if (b < 128){
    float acc = 0.f;
    for (int m = 0; m < 128; ++m) acc += W1w[m*128 + b] * C2t[m*128 + o];
    ws[WP_OFF + b*128 + o] = acc;
  } else {
    float acc = 0.f;
    for (int m = 0; m < 128; ++m) acc += W1b[m] * C2t[m*128 + o];
    ws[BA_OFF + 128 + o] = acc;
  }
}

// ---------------- merged: bucket histogram (blocks <NCB) + X->bf16 (rest) ----------------
__global__ __launch_bounds__(256) void count_tobf16(
        const int* __restrict__ vertex, const int* __restrict__ edges,
        const float* __restrict__ X,
        int* __restrict__ bcntE, int* __restrict__ bcntV,
        unsigned short* __restrict__ Xbf){
  int b = blockIdx.x, t = threadIdx.x;
  __shared__ int hE[256], hV[256];
  if (b < NCB){
    hE[t] = 0; hV[t] = 0;
    __syncthreads();
    int i0 = b * 2048;
    #pragma unroll
    for (int r = 0; r < 8; ++r){
      int i = i0 + r*256 + t;
      if (i < NNZV){
        atomicAdd(&hE[edges[i]  >> 6], 1);
        atomicAdd(&hV[vertex[i] >> 8], 1);
      }
    }
    __syncthreads();
    if (hE[t]) atomicAdd(bcntE + t, hE[t]);
    if (hV[t]) atomicAdd(bcntV + t, hV[t]);
  } else {
    int i = (b - NCB)*256 + t;
    if (i < NV*DIM/8){
      float4 v0 = ((const float4*)X)[(size_t)i*2];
      float4 v1 = ((const float4*)X)[(size_t)i*2 + 1];
      ushort4 h0, h1;
      h0.x=f2bf(v0.x); h0.y=f2bf(v0.y); h0.z=f2bf(v0.z); h0.w=f2bf(v0.w);
      h1.x=f2bf(v1.x); h1.y=f2bf(v1.y); h1.z=f2bf(v1.z); h1.w=f2bf(v1.w);
      ((ushort4*)Xbf)[(size_t)i*2]     = h0;
      ((ushort4*)Xbf)[(size_t)i*2 + 1] = h1;
    }
  }
}

// ---------------- tiny: scan bucket counts, init cursors, set tail offs ----------------
__global__ __launch_bounds__(256) void scan_buckets(
        const int* __restrict__ bcntE, const int* __restrict__ bcntV,
        int* __restrict__ bOffE, int* __restrict__ bOffV,
        int* __restrict__ bcurE, int* __restrict__ bcurV,
        int* __restrict__ offE, int* __restrict__ offV){
  __shared__ int s[256];
  int t = threadIdx.x;
  int c = (t < NBKE) ? bcntE[t] : 0;
  s[t] = c; __syncthreads();
  for (int d = 1; d < 256; d <<= 1){
    int x = (t >= d) ? s[t-d] : 0;
    __syncthreads(); s[t] += x; __syncthreads();
  }
  if (t < NBKE){ bOffE[t] = s[t] - c; bcurE[t] = s[t] - c; }
  if (t == 0){ bOffE[NBKE] = NNZV; offE[NEV] = NNZV; }
  __syncthreads();
  int c2 = (t < NBKV) ? bcntV[t] : 0;
  s[t] = c2; __syncthreads();
  for (int d = 1; d < 256; d <<= 1){
    int x = (t >= d) ? s[t-d] : 0;
    __syncthreads(); s[t] += x; __syncthreads();
  }
  if (t < NBKV){ bOffV[t] = s[t] - c2; bcurV[t] = s[t] - c2; }
  if (t == 0){ bOffV[NBKV] = NNZV; offV[NV] = NNZV; }
}

// ---------------- fused binning: one pass produces PE and PV ----------------
__global__ __launch_bounds__(256) void fill_binned2(
        const int* __restrict__ vertex, const int* __restrict__ edges,
        const float* __restrict__ alpha,
        int* __restrict__ bcurE, int* __restrict__ bcurV,
        int2* __restrict__ PE, int2* __restrict__ PV){
  __shared__ int histE[256], lofsE[256], gbaseE[256], posE[256];
  __shared__ int histV[256], lofsV[256], gbaseV[256], posV[256];
  __shared__ int ss[256];
  __shared__ int2 stgE[CH2], stgV[CH2];
  int t = threadIdx.x;
  int i0 = blockIdx.x * CH2;
  histE[t] = 0; histV[t] = 0;
  __syncthreads();
  int pkE[8], pkV[8], pa[8];
  #pragma unroll
  for (int r = 0; r < 8; ++r){
    int i = i0 + r*256 + t;
    int pe = -1, pv = -1, ab = 0;
    if (i < NNZV){
      int v = vertex[i], e = edges[i];
      ab = __float_as_int(alpha[i]);
      pe = (e << 16) | v;              // pe>>22 == e>>6
      pv = (v << 14) | e;              // pv>>22 == v>>8
      atomicAdd(&histE[pe >> 22], 1);
      atomicAdd(&histV[pv >> 22], 1);
    }
    pkE[r] = pe; pkV[r] = pv; pa[r] = ab;
  }
  __syncthreads();
  int cE = histE[t];
  ss[t] = cE; __syncthreads();
  for (int d = 1; d < 256; d <<= 1){
    int x = (t >= d) ? ss[t-d] : 0;
    __syncthreads(); ss[t] += x; __syncthreads();
  }
  lofsE[t] = ss[t] - cE; posE[t] = ss[t] - cE;
  __syncthreads();
  int cV = histV[t];
  ss[t] = cV; __syncthreads();
  for (int d = 1; d < 256; d <<= 1){
    int x = (t >= d) ? ss[t-d] : 0;
    __syncthreads(); ss[t] += x; __syncthreads();
  }
  lofsV[t] = ss[t] - cV; posV[t] = ss[t] - cV;
  __syncthreads();
  #pragma unroll
  for (int r = 0; r < 8; ++r){
    if (pkE[r] != -1){
      int p = atomicAdd(&posE[pkE[r] >> 22], 1);
      stgE[p] = make_int2(pkE[r], pa[r]);
      int q = atomicAdd(&posV[pkV[r] >> 22], 1);
      stgV[q] = make_int2(pkV[r], pa[r]);
    }
  }
  __syncthreads();
  {
    int cnt = histE[t];
    gbaseE[t] = cnt ? atomicAdd(&bcurE[t], cnt) : 0;
    int cnt2 = histV[t];
    gbaseV[t] = cnt2 ? atomicAdd(&bcurV[t], cnt2) : 0;
  }
  __syncthreads();
  int total = min(CH2, NNZV - i0);
  for (int s = t; s < total; s += 256){
    int lo = 0, hi = NBKE - 1;
    while (lo < hi){ int mid = (lo + hi + 1) >> 1; if (lofsE[mid] <= s) lo = mid; else hi = mid - 1; }
    PE[gbaseE[lo] + (s - lofsE[lo])] = stgE[s];
    lo = 0; hi = NBKV - 1;
    while (lo < hi){ int mid = (lo + hi + 1) >> 1; if (lofsV[mid] <= s) lo = mid; else hi = mid - 1; }
    PV[gbaseV[lo] + (s - lofsV[lo])] = stgV[s];
  }
}

// ---------------- in-bucket counting sort + exact-key off + alpha sums ----------------
__global__ __launch_bounds__(256) void sort_bucket(
        int2* __restrict__ pairs, const int* __restrict__ bOff,
        int* __restrict__ off, float* __restrict__ sums,
        int2* __restrict__ bounce, int kpb, int shift, int nkeys){
  int b = blockIdx.x, t = threadIdx.x;
  int k0 = b * kpb;
  int r0 = bOff[b], r1 = bOff[b+1];
  int m = r1 - r0;
  __shared__ int hist[256], rnk[256], ssc[256];
  __shared__ int2 srt[SCAP];
  for (int q = t; q < kpb; q += 256) hist[q] = 0;
  __syncthreads();
  int px[30], py[30];
  #pragma unroll
  for (int r = 0; r < 30; ++r){
    int s = r*256 + t;
    int x = -1, y = 0;
    if (s < m && m <= SCAP){
      int2 p = pairs[r0 + s];
      x = p.x; y = p.y;
      atomicAdd(&hist[(x >> shift) - k0], 1);
    }
    px[r] = x; py[r] = y;
  }
  if (m > SCAP){   // statistically never taken; correct fallback via global bounce
    for (int s = t; s < m; s += 256){
      int2 p = pairs[r0 + s];
      bounce[s] = p;
      atomicAdd(&hist[(p.x >> shift) - k0], 1);
    }
  }
  __syncthreads();
  int c = (t < kpb) ? hist[t] : 0;
  ssc[t] = c; __syncthreads();
  for (int d = 1; d < 256; d <<= 1){
    int x = (t >= d) ? ssc[t-d] : 0;
    __syncthreads(); ssc[t] += x; __syncthreads();
  }
  if (t < kpb){
    rnk[t] = ssc[t] - c;
    int k = k0 + t;
    if (k < nkeys) off[k] = r0 + ssc[t] - c;
  }
  __syncthreads();
  if (m <= SCAP){
    #pragma unroll
    for (int r = 0; r < 30; ++r){
      if (px[r] >= 0){
        int p = atomicAdd(&rnk[(px[r] >> shift) - k0], 1);
        srt[p] = make_int2(px[r], py[r]);
      }
    }
    __syncthreads();
    for (int s = t; s < m; s += 256) pairs[r0 + s] = srt[s];
    if (t < kpb){
      int k = k0 + t;
      if (k < nkeys){
        float sa = 0.f;
        int s0 = ssc[t] - hist[t], s1 = ssc[t];
        for (int s = s0; s < s1; ++s) sa += __int_as_float(srt[s].y);
        sums[k] = sa;
      }
    }
  } else {
    __syncthreads();
    for (int s = t; s < m; s += 256){
      int2 p = bounce[s];
      int q = atomicAdd(&rnk[(p.x >> shift) - k0], 1);
      pairs[r0 + q] = p;
    }
    __syncthreads();
    if (t < kpb){
      int k = k0 + t;
      if (k < nkeys){
        float sa = 0.f;
        int s0 = ssc[t] - hist[t], s1 = ssc[t];
        for (int s = s0; s < s1; ++s) sa += __int_as_float(pairs[r0 + s].y);
        sums[k] = sa;
      }
    }
  }
}

// ---------------- wave-per-edge reduce: T[e] = sum a*Xbf[v]  (8-deep pipeline) ----------------
__global__ __launch_bounds__(256) void edge_reduce(
        const unsigned short* __restrict__ Xbf, const int* __restrict__ offE,
        const int2* __restrict__ PE, float* __restrict__ T){
  int w = threadIdx.x >> 6, l = threadIdx.x & 63;
  int e = blockIdx.x*4 + w;
  int s0 = offE[e], s1 = offE[e+1];
  float acc0 = 0.f, acc1 = 0.f;
  int j = s0;
  for (; j + 8 <= s1; j += 8){
    int2 p[8];
    #pragma unroll
    for (int q = 0; q < 8; ++q) p[q] = PE[j + q];
    float x0[8], x1[8];
    #pragma unroll
    for (int q = 0; q < 8; ++q){
      int v = (p[q].x & 0xFFFF) << 7;
      x0[q] = bf2f(Xbf[v + l]);
      x1[q] = bf2f(Xbf[v + 64 + l]);
    }
    #pragma unroll
    for (int q = 0; q < 8; ++q){
      float a = __int_as_float(p[q].y);
      acc0 += a * x0[q]; acc1 += a * x1[q];
    }
  }
  for (; j < s1; ++j){
    int2 p = PE[j];
    int v = (p.x & 0xFFFF) << 7;
    float a = __int_as_float(p.y);
    acc0 += a * bf2f(Xbf[v + l]);
    acc1 += a * bf2f(Xbf[v + 64 + l]);
  }
  size_t o = (size_t)e * DIM;
  T[o + l]      = acc0;
  T[o + 64 + l] = acc1;
}

// ---------------- Ye = T @ W'' + B*b1C2  (writes bf16 XEBF) ----------------
__global__ __launch_bounds__(256) void gemm_ye(float* __restrict__ ws){
  __shared__ float Y[32][136];
  const float* T   = ws + T_OFF;
  const float* WP  = ws + WP_OFF;
  const float* Bs  = ws + B_OFF;
  const float* b1p = ws + BA_OFF + 128;
  unsigned short* Ye = (unsigned short*)(ws + XEBF_OFF);
  int n0 = blockIdx.x * 32;
  int tid = threadIdx.x;
  {
    int lr = tid >> 3, lj = tid & 7;
    int gn = n0 + lr; if (gn >= NEV) gn = NEV - 1;
    const float* src = T + (size_t)gn*DIM + lj*16;
    #pragma unroll
    for (int q = 0; q < 4; ++q)
      *(float4*)(&Y[lr][lj*16 + q*4]) = *(const float4*)(src + q*4);
  }
  __syncthreads();
  int rq = tid >> 5, cq = tid & 31;
  float acc[4][4];
  #pragma unroll
  for (int u=0;u<4;++u){ acc[u][0]=0;acc[u][1]=0;acc[u][2]=0;acc[u][3]=0; }
  const float* Crow = WP + cq*4;
  #pragma unroll 4
  for (int k = 0; k < 128; ++k){
    float4 c = *(const float4*)(Crow + (size_t)k*128);
    #pragma unroll
    for (int u = 0; u < 4; ++u){
      float y = Y[rq*4 + u][k];
      acc[u][0] += y*c.x; acc[u][1] += y*c.y; acc[u][2] += y*c.z; acc[u][3] += y*c.w;
    }
  }
  float4 b1v = *(const float4*)(b1p + cq*4);
  #pragma unroll
  for (int u = 0; u < 4; ++u){
    int e = n0 + rq*4 + u;
    if (e < NEV){
      float Bv = Bs[e];
      ushort4 h;
      h.x = f2bf(acc[u][0] + Bv*b1v.x); h.y = f2bf(acc[u][1] + Bv*b1v.y);
      h.z = f2bf(acc[u][2] + Bv*b1v.z); h.w = f2bf(acc[u][3] + Bv*b1v.w);
      *(ushort4*)(Ye + (size_t)e*DIM + cq*4) = h;
    }
  }
}

// ---------------- R = [Av*X | X0] @ [C1;C3] + Av*bA + Wb  (writes d_out rows) ----------------
#define LDS_STRIDE 264   // shorts per row: 256 + 8 pad

__global__ __launch_bounds__(256) void gemm_pq(
        const float* __restrict__ X, const float* __restrict__ X0,
        const float* __restrict__ Wb, const float* __restrict__ ws,
        float* __restrict__ R){
  __shared__ unsigned short At[64 * LDS_STRIDE];
  __shared__ float ArS[64];
  const float* Aa = ws + A_OFF;
  const float* bA = ws + BA_OFF;
  const unsigned short* Bpack = (const unsigned short*)(ws + BPACK_OFF);
  int r0 = blockIdx.x * 64;
  int t = threadIdx.x;
  if (t < 64){
    int gn = r0 + t; if (gn >= NV) gn = NV - 1;
    ArS[t] = Aa[gn];
  }
  __syncthreads();
  #pragma unroll
  for (int seg = 0; seg < 2; ++seg){
    const float* src = (seg == 0) ? X : X0;
    #pragma unroll
    for (int i = 0; i < 8; ++i){
      int idx = t + i*256;
      int row = idx >> 5;
      int c4  = idx & 31;
      int gn = r0 + row; if (gn >= NV) gn = NV - 1;
      float4 v = *(const float4*)(src + (size_t)gn*DIM + c4*4);
      if (seg == 0){
        float Ar = ArS[row];
        v.x *= Ar; v.y *= Ar; v.z *= Ar; v.w *= Ar;
      }
      ushort4 h;
      h.x = f2bf(v.x); h.y = f2bf(v.y); h.z = f2bf(v.z); h.w = f2bf(v.w);
      *(ushort4*)(&At[row*LDS_STRIDE + seg*128 + c4*4]) = h;
    }
  }
  __syncthreads();

  int w = t >> 6, l = t & 63;
  int m0 = w * 16;
  int lr = l & 15, lg = l >> 4;
  f32x4 acc[8];
  #pragma unroll
  for (int ct = 0; ct < 8; ++ct) acc[ct] = (f32x4){0.f,0.f,0.f,0.f};

  const unsigned short* arow = &At[(m0 + lr)*LDS_STRIDE + lg*8];
  #pragma unroll
  for (int ks = 0; ks < 8; ++ks){
    bf16x8 af = *(const bf16x8*)(arow + ks*32);
    const bf16x8* bp = (const bf16x8*)(Bpack) + (size_t)ks*8*64 + l;
    #pragma unroll
    for (int ct = 0; ct < 8; ++ct){
      bf16x8 bf = bp[ct*64];
      acc[ct] = __builtin_amdgcn_mfma_f32_16x16x32_bf16(af, bf, acc[ct], 0, 0, 0);
    }
  }

  #pragma unroll
  for (int ct = 0; ct < 8; ++ct){
    int o = ct*16 + lr;
    float ba = bA[o], wb = Wb[o];
    #pragma unroll
    for (int r = 0; r < 4; ++r){
      int lrow = m0 + lg*4 + r;
      int row = r0 + lrow;
      if (row < NV){
        float Av = ArS[lrow];
        R[(size_t)row*DIM + o] = acc[ct][r] + Av*ba + wb;
      }
    }
  }
}

// ---------------- wave-per-vertex: out[v] += sum a*Ye[e]  (8-deep pipeline) ----------------
__global__ __launch_bounds__(256) void vertex_fused(
        const unsigned short* __restrict__ Ye, const int* __restrict__ offV,
        const int2* __restrict__ PV, float* __restrict__ out){
  int w = threadIdx.x >> 6, l = threadIdx.x & 63;
  int v = blockIdx.x*4 + w;
  int s0 = offV[v], s1 = offV[v+1];
  float acc0 = 0.f, acc1 = 0.f;
  int j = s0;
  for (; j + 8 <= s1; j += 8){
    int2 p[8];
    #pragma unroll
    for (int q = 0; q < 8; ++q) p[q] = PV[j + q];
    float y0[8], y1[8];
    #pragma unroll
    for (int q = 0; q < 8; ++q){
      int e = (p[q].x & 0x3FFF) << 7;
      y0[q] = bf2f(Ye[e + l]);
      y1[q] = bf2f(Ye[e + 64 + l]);
    }
    #pragma unroll
    for (int q = 0; q < 8; ++q){
      float a = __int_as_float(p[q].y);
      acc0 += a * y0[q]; acc1 += a * y1[q];
    }
  }
  for (; j < s1; ++j){
    int2 p = PV[j];
    int e = (p.x & 0x3FFF) << 7;
    float a = __int_as_float(p.y);
    acc0 += a * bf2f(Ye[e + l]);
    acc1 += a * bf2f(Ye[e + 64 + l]);
  }
  size_t o = (size_t)v * DIM;
  out[o + l]      += acc0;   // R already there; same thread, same address
  out[o + 64 + l] += acc1;
}

extern "C" void kernel_launch(void* const* d_in, const int* in_sizes, int n_in,
                              void* d_out, int out_size, void* d_ws, size_t ws_size,
                              hipStream_t stream){
  const float* X    = (const float*)d_in[0];
  const int*  vertex= (const int*)  d_in[1];
  const int*  edges = (const int*)  d_in[2];
  const float* X0   = (const float*)d_in[3];
  const float* alpha= (const float*)d_in[4];
  const float* W1w  = (const float*)d_in[5];
  const float* W1b  = (const float*)d_in[6];
  const float* W2w  = (const float*)d_in[7];
  const float* W2b  = (const float*)d_in[8];
  const float* Ww   = (const float*)d_in[9];
  const float* Wb   = (const float*)d_in[10];
  float* out = (float*)d_out;
  float* ws  = (float*)d_ws;

  int* bcntE = (int*)(ws + BCNTE_OFF);
  int* bOffE = (int*)(ws + BOFFE_OFF);
  int* bcntV = (int*)(ws + BCNTV_OFF);
  int* bOffV = (int*)(ws + BOFFV_OFF);
  int* offE  = (int*)(ws + OFFE_OFF);
  int* bcurE = (int*)(ws + CURE_OFF);
  int* offV  = (int*)(ws + OFFV_OFF);
  int* bcurV = (int*)(ws + CURV_OFF);
  int2* PV   = (int2*)(ws + PV_OFF);
  int2* PE   = (int2*)(out + PE_OUT_FLOAT_OFF);
  int2* bounce = (int2*)(ws + T_OFF);
  unsigned short* Xbf = (unsigned short*)out;           // front 12.8 MB of d_out
  unsigned short* Ye  = (unsigned short*)(ws + XEBF_OFF);

  prep1        <<<389, 128, 0, stream>>>(W2w, W2b, Ww, ws);
  prep2        <<<129, 128, 0, stream>>>(W1w, W1b, ws);
  count_tobf16 <<<NCB + (NV*DIM/8 + 255)/256, 256, 0, stream>>>(vertex, edges, X,
                                                                bcntE, bcntV, Xbf);
  scan_buckets <<<1, 256, 0, stream>>>(bcntE, bcntV, bOffE, bOffV, bcurE, bcurV,
                                       offE, offV);
  fill_binned2 <<<(NNZV + CH2 - 1)/CH2, 256, 0, stream>>>(vertex, edges, alpha,
                                                          bcurE, bcurV, PE, PV);
  sort_bucket  <<<NBKE, 256, 0, stream>>>(PE, bOffE, offE, ws + B_OFF, bounce, 64,  16, NEV);
  sort_bucket  <<<NBKV, 256, 0, stream>>>(PV, bOffV, offV, ws + A_OFF, bounce, 256, 14, NV);
  edge_reduce  <<<NEV/4, 256, 0, stream>>>(Xbf, offE, PE, ws + T_OFF);
  gemm_ye      <<<(NEV + 31)/32, 256, 0, stream>>>(ws);
  gemm_pq      <<<(NV + 63)/64, 256, 0, stream>>>(X, X0, Wb, ws, out);
  vertex_fused <<<NV/4, 256, 0, stream>>>(Ye, offV, PV, out);
}

// Round 14
// 179.701 us; speedup vs baseline: 1.4289x; 1.0097x over previous
//
#include <hip/hip_runtime.h>

#define NV   50000
#define NEV  10000
#define NNZV 600000
#define DIM  128

#define NBKE 157    // edge buckets: e>>6  (64 keys each)
#define NBKV 196    // vertex buckets: v>>8 (256 keys each)
#define NCB  293    // count blocks (2048 items each)
#define CH2  2048   // fused fill chunk
#define SCAP 7680

// workspace layout (float offsets) — total 3,401,920 floats = 13.6 MB (proven)
#define BPACK_OFF 0        // 16384: bf16 256x128 packed [C1;C3] (32768 ushorts)
#define WP_OFF    24576    // 16384: W'' = W1^T @ C2, f32 [k][o]
#define BA_OFF    40960    // 256: bA[0..128), b1C2[128..256)
#define A_OFF     41216    // 50048: per-vertex alpha sum
#define B_OFF     91264    // 10048: per-edge alpha sum
#define T_OFF     101312   // 1280000: f32 T; also C2tmp during prep + int2 bounce
#define XEBF_OFF  1381312  // 640000 floats: bf16 Ye (1.28M ushort)
#define BCNTE_OFF 2021312  // int 256
#define BOFFE_OFF 2021568  // int 256
#define BCNTV_OFF 2021824  // int 256
#define BOFFV_OFF 2022080  // int 256
#define OFFE_OFF  2031328  // int 10016: exact-key CSR offsets (edges)
#define CURE_OFF  2041344  // int (bcurE uses first 157)
#define OFFV_OFF  2101376  // int 50016: exact-key CSR offsets (vertices)
#define CURV_OFF  2151392  // int (bcurV uses first 196)
#define PV_OFF    2201920  // int2 600000: (v<<14|e, alpha) grouped by vertex
// d_out timeline: Xbf (bf16 X, front 12.8MB) + PE pairs (int2 at float 3.2M) are
// written early, consumed by edge_reduce, then gemm_pq overwrites ALL of d_out
// with R rows; vertex_fused does wave-local RMW of its own row.
#define PE_OUT_FLOAT_OFF 3200000

typedef __attribute__((ext_vector_type(8))) short bf16x8;
typedef __attribute__((ext_vector_type(4))) float f32x4;

__device__ __forceinline__ unsigned short f2bf(float x){
  unsigned u = __float_as_uint(x);
  u += 0x7fffu + ((u >> 16) & 1u);     // round-to-nearest-even
  return (unsigned short)(u >> 16);
}
__device__ __forceinline__ float bf2f(unsigned short h){
  return __uint_as_float((unsigned)h << 16);
}

// ---------------- prep1: pack [C1;C3], C2tmp, bA; blocks 385-388 zero counts ----------------
__global__ __launch_bounds__(128) void prep1(
        const float* __restrict__ W2w, const float* __restrict__ W2b,
        const float* __restrict__ Ww, float* __restrict__ ws){
  int b = blockIdx.x, o = threadIdx.x;
  if (b < 256){
    float s;
    if (b < 128){            // C1[k=b][o] = 0.5*sum_m Ww[o][m]*W2w[m][b]
      float acc = 0.f;
      for (int m = 0; m < 128; ++m) acc += Ww[o*128 + m] * W2w[m*256 + b];
      s = 0.5f * acc;
    } else {                 // C3[k=b-128][o] = 0.5*Ww[o][b-128]
      s = 0.5f * Ww[o*128 + (b - 128)];
    }
    int ks = b >> 5, g = (b >> 3) & 3, j = b & 7;
    int ct = o >> 4, lo = o & 15;
    unsigned short* Bp = (unsigned short*)(ws + BPACK_OFF);
    Bp[((size_t)((ks*8 + ct)*64 + g*16 + lo))*8 + j] = f2bf(s);
  } else if (b < 384){       // C2tmp[m][o]
    int m = b - 256;
    float acc = 0.f;
    for (int j = 0; j < 128; ++j) acc += Ww[o*128 + j] * W2w[j*256 + 128 + m];
    ws[T_OFF + m*128 + o] = 0.5f * acc;
  } else if (b == 384){      // bA
    float acc = 0.f;
    for (int m = 0; m < 128; ++m) acc += Ww[o*128 + m] * W2b[m];
    ws[BA_OFF + o] = 0.5f * acc;
  } else {                   // zero the 1024-int bcnt/bOff block
    int* z = (int*)(ws + BCNTE_OFF);
    int base = (b - 385)*256;
    z[base + o] = 0; z[base + 128 + o] = 0;
  }
}

// ---------------- prep2: W'' = W1^T @ C2tmp; b1C2 ----------------
__global__ __launch_bounds__(128) void prep2(
        const float* __restrict__ W1w, const float* __restrict__ W1b,
        float* __restrict__ ws){
  int b = blockIdx.x, o = threadIdx.x;
  const float* C2t = ws + T_OFF;
  if (b < 128){
    float acc = 0.f;
    for (int m = 0; m < 128; ++m) acc += W1w[m*128 + b] * C2t[m*128 + o];
    ws[WP_OFF + b*128 + o] = acc;
  } else {
    float acc = 0.f;
    for (int m = 0; m < 128; ++m) acc += W1b[m] * C2t[m*128 + o];
    ws[BA_OFF + 128 + o] = acc;
  }
}

// ---------------- merged: bucket histogram (blocks <NCB) + X->bf16 (rest) ----------------
__global__ __launch_bounds__(256) void count_tobf16(
        const int* __restrict__ vertex, const int* __restrict__ edges,
        const float* __restrict__ X,
        int* __restrict__ bcntE, int* __restrict__ bcntV,
        unsigned short* __restrict__ Xbf){
  int b = blockIdx.x, t = threadIdx.x;
  __shared__ int hE[256], hV[256];
  if (b < NCB){
    hE[t] = 0; hV[t] = 0;
    __syncthreads();
    int i0 = b * 2048;
    #pragma unroll
    for (int r = 0; r < 8; ++r){
      int i = i0 + r*256 + t;
      if (i < NNZV){
        atomicAdd(&hE[edges[i]  >> 6], 1);
        atomicAdd(&hV[vertex[i] >> 8], 1);
      }
    }
    __syncthreads();
    if (hE[t]) atomicAdd(bcntE + t, hE[t]);
    if (hV[t]) atomicAdd(bcntV + t, hV[t]);
  } else {
    int i = (b - NCB)*256 + t;
    if (i < NV*DIM/8){
      float4 v0 = ((const float4*)X)[(size_t)i*2];
      float4 v1 = ((const float4*)X)[(size_t)i*2 + 1];
      ushort4 h0, h1;
      h0.x=f2bf(v0.x); h0.y=f2bf(v0.y); h0.z=f2bf(v0.z); h0.w=f2bf(v0.w);
      h1.x=f2bf(v1.x); h1.y=f2bf(v1.y); h1.z=f2bf(v1.z); h1.w=f2bf(v1.w);
      ((ushort4*)Xbf)[(size_t)i*2]     = h0;
      ((ushort4*)Xbf)[(size_t)i*2 + 1] = h1;
    }
  }
}

// ---------------- tiny: scan bucket counts, init cursors, set tail offs ----------------
__global__ __launch_bounds__(256) void scan_buckets(
        const int* __restrict__ bcntE, const int* __restrict__ bcntV,
        int* __restrict__ bOffE, int* __restrict__ bOffV,
        int* __restrict__ bcurE, int* __restrict__ bcurV,
        int* __restrict__ offE, int* __restrict__ offV){
  __shared__ int s[256];
  int t = threadIdx.x;
  int c = (t < NBKE) ? bcntE[t] : 0;
  s[t] = c; __syncthreads();
  for (int d = 1; d < 256; d <<= 1){
    int x = (t >= d) ? s[t-d] : 0;
    __syncthreads(); s[t] += x; __syncthreads();
  }
  if (t < NBKE){ bOffE[t] = s[t] - c; bcurE[t] = s[t] - c; }
  if (t == 0){ bOffE[NBKE] = NNZV; offE[NEV] = NNZV; }
  __syncthreads();
  int c2 = (t < NBKV) ? bcntV[t] : 0;
  s[t] = c2; __syncthreads();
  for (int d = 1; d < 256; d <<= 1){
    int x = (t >= d) ? s[t-d] : 0;
    __syncthreads(); s[t] += x; __syncthreads();
  }
  if (t < NBKV){ bOffV[t] = s[t] - c2; bcurV[t] = s[t] - c2; }
  if (t == 0){ bOffV[NBKV] = NNZV; offV[NV] = NNZV; }
}

// ---------------- fused binning: one pass produces PE and PV ----------------
__global__ __launch_bounds__(256) void fill_binned2(
        const int* __restrict__ vertex, const int* __restrict__ edges,
        const float* __restrict__ alpha,
        int* __restrict__ bcurE, int* __restrict__ bcurV,
        int2* __restrict__ PE, int2* __restrict__ PV){
  __shared__ int histE[256], lofsE[256], gbaseE[256], posE[256];
  __shared__ int histV[256], lofsV[256], gbaseV[256], posV[256];
  __shared__ int ss[256];
  __shared__ int2 stgE[CH2], stgV[CH2];
  int t = threadIdx.x;
  int i0 = blockIdx.x * CH2;
  histE[t] = 0; histV[t] = 0;
  __syncthreads();
  int pkE[8], pkV[8], pa[8];
  #pragma unroll
  for (int r = 0; r < 8; ++r){
    int i = i0 + r*256 + t;
    int pe = -1, pv = -1, ab = 0;
    if (i < NNZV){
      int v = vertex[i], e = edges[i];
      ab = __float_as_int(alpha[i]);
      pe = (e << 16) | v;              // pe>>22 == e>>6
      pv = (v << 14) | e;              // pv>>22 == v>>8
      atomicAdd(&histE[pe >> 22], 1);
      atomicAdd(&histV[pv >> 22], 1);
    }
    pkE[r] = pe; pkV[r] = pv; pa[r] = ab;
  }
  __syncthreads();
  int cE = histE[t];
  ss[t] = cE; __syncthreads();
  for (int d = 1; d < 256; d <<= 1){
    int x = (t >= d) ? ss[t-d] : 0;
    __syncthreads(); ss[t] += x; __syncthreads();
  }
  lofsE[t] = ss[t] - cE; posE[t] = ss[t] - cE;
  __syncthreads();
  int cV = histV[t];
  ss[t] = cV; __syncthreads();
  for (int d = 1; d < 256; d <<= 1){
    int x = (t >= d) ? ss[t-d] : 0;
    __syncthreads(); ss[t] += x; __syncthreads();
  }
  lofsV[t] = ss[t] - cV; posV[t] = ss[t] - cV;
  __syncthreads();
  #pragma unroll
  for (int r = 0; r < 8; ++r){
    if (pkE[r] != -1){
      int p = atomicAdd(&posE[pkE[r] >> 22], 1);
      stgE[p] = make_int2(pkE[r], pa[r]);
      int q = atomicAdd(&posV[pkV[r] >> 22], 1);
      stgV[q] = make_int2(pkV[r], pa[r]);
    }
  }
  __syncthreads();
  {
    int cnt = histE[t];
    gbaseE[t] = cnt ? atomicAdd(&bcurE[t], cnt) : 0;
    int cnt2 = histV[t];
    gbaseV[t] = cnt2 ? atomicAdd(&bcurV[t], cnt2) : 0;
  }
  __syncthreads();
  int total = min(CH2, NNZV - i0);
  for (int s = t; s < total; s += 256){
    int lo = 0, hi = NBKE - 1;
    while (lo < hi){ int mid = (lo + hi + 1) >> 1; if (lofsE[mid] <= s) lo = mid; else hi = mid - 1; }
    PE[gbaseE[lo] + (s - lofsE[lo])] = stgE[s];
    lo = 0; hi = NBKV - 1;
    while (lo < hi){ int mid = (lo + hi + 1) >> 1; if (lofsV[mid] <= s) lo = mid; else hi = mid - 1; }
    PV[gbaseV[lo] + (s - lofsV[lo])] = stgV[s];
  }
}

// ---------------- in-bucket counting sort + exact-key off + alpha sums ----------------
__global__ __launch_bounds__(256) void sort_bucket(
        int2* __restrict__ pairs, const int* __restrict__ bOff,
        int* __restrict__ off, float* __restrict__ sums,
        int2* __restrict__ bounce, int kpb, int shift, int nkeys){
  int b = blockIdx.x, t = threadIdx.x;
  int k0 = b * kpb;
  int r0 = bOff[b], r1 = bOff[b+1];
  int m = r1 - r0;
  __shared__ int hist[256], rnk[256], ssc[256];
  __shared__ int2 srt[SCAP];
  for (int q = t; q < kpb; q += 256) hist[q] = 0;
  __syncthreads();
  int px[30], py[30];
  #pragma unroll
  for (int r = 0; r < 30; ++r){
    int s = r*256 + t;
    int x = -1, y = 0;
    if (s < m && m <= SCAP){
      int2 p = pairs[r0 + s];
      x = p.x; y = p.y;
      atomicAdd(&hist[(x >> shift) - k0], 1);
    }
    px[r] = x; py[r] = y;
  }
  if (m > SCAP){   // statistically never taken; correct fallback via global bounce
    for (int s = t; s < m; s += 256){
      int2 p = pairs[r0 + s];
      bounce[s] = p;
      atomicAdd(&hist[(p.x >> shift) - k0], 1);
    }
  }
  __syncthreads();
  int c = (t < kpb) ? hist[t] : 0;
  ssc[t] = c; __syncthreads();
  for (int d = 1; d < 256; d <<= 1){
    int x = (t >= d) ? ssc[t-d] : 0;
    __syncthreads(); ssc[t] += x; __syncthreads();
  }
  if (t < kpb){
    rnk[t] = ssc[t] - c;
    int k = k0 + t;
    if (k < nkeys) off[k] = r0 + ssc[t] - c;
  }
  __syncthreads();
  if (m <= SCAP){
    #pragma unroll
    for (int r = 0; r < 30; ++r){
      if (px[r] >= 0){
        int p = atomicAdd(&rnk[(px[r] >> shift) - k0], 1);
        srt[p] = make_int2(px[r], py[r]);
      }
    }
    __syncthreads();
    for (int s = t; s < m; s += 256) pairs[r0 + s] = srt[s];
    if (t < kpb){
      int k = k0 + t;
      if (k < nkeys){
        float sa = 0.f;
        int s0 = ssc[t] - hist[t], s1 = ssc[t];
        for (int s = s0; s < s1; ++s) sa += __int_as_float(srt[s].y);
        sums[k] = sa;
      }
    }
  } else {
    __syncthreads();
    for (int s = t; s < m; s += 256){
      int2 p = bounce[s];
      int q = atomicAdd(&rnk[(p.x >> shift) - k0], 1);
      pairs[r0 + q] = p;
    }
    __syncthreads();
    if (t < kpb){
      int k = k0 + t;
      if (k < nkeys){
        float sa = 0.f;
        int s0 = ssc[t] - hist[t], s1 = ssc[t];
        for (int s = s0; s < s1; ++s) sa += __int_as_float(pairs[r0 + s].y);
        sums[k] = sa;
      }
    }
  }
}

// ---------------- wave-per-edge reduce: T[e] = sum a*Xbf[v]  (ushort2 gathers) ----------------
__global__ __launch_bounds__(256) void edge_reduce(
        const unsigned short* __restrict__ Xbf, const int* __restrict__ offE,
        const int2* __restrict__ PE, float* __restrict__ T){
  int w = threadIdx.x >> 6, l = threadIdx.x & 63;
  int e = blockIdx.x*4 + w;
  int s0 = offE[e], s1 = offE[e+1];
  float acc0 = 0.f, acc1 = 0.f;
  int j = s0;
  for (; j + 8 <= s1; j += 8){
    int2 p[8];
    #pragma unroll
    for (int q = 0; q < 8; ++q) p[q] = PE[j + q];
    float lo[8], hi[8];
    #pragma unroll
    for (int q = 0; q < 8; ++q){
      int v = (p[q].x & 0xFFFF) << 7;
      unsigned xx = *(const unsigned*)(Xbf + v + 2*l);
      lo[q] = bf2f((unsigned short)(xx & 0xFFFF));
      hi[q] = bf2f((unsigned short)(xx >> 16));
    }
    #pragma unroll
    for (int q = 0; q < 8; ++q){
      float a = __int_as_float(p[q].y);
      acc0 += a * lo[q]; acc1 += a * hi[q];
    }
  }
  for (; j < s1; ++j){
    int2 p = PE[j];
    int v = (p.x & 0xFFFF) << 7;
    unsigned xx = *(const unsigned*)(Xbf + v + 2*l);
    float a = __int_as_float(p.y);
    acc0 += a * bf2f((unsigned short)(xx & 0xFFFF));
    acc1 += a * bf2f((unsigned short)(xx >> 16));
  }
  float2 o2; o2.x = acc0; o2.y = acc1;
  *(float2*)(T + (size_t)e*DIM + 2*l) = o2;
}

// ---------------- Ye = T @ W'' + B*b1C2  (writes bf16 XEBF) ----------------
__global__ __launch_bounds__(256) void gemm_ye(float* __restrict__ ws){
  __shared__ float Y[32][136];
  const float* T   = ws + T_OFF;
  const float* WP  = ws + WP_OFF;
  const float* Bs  = ws + B_OFF;
  const float* b1p = ws + BA_OFF + 128;
  unsigned short* Ye = (unsigned short*)(ws + XEBF_OFF);
  int n0 = blockIdx.x * 32;
  int tid = threadIdx.x;
  {
    int lr = tid >> 3, lj = tid & 7;
    int gn = n0 + lr; if (gn >= NEV) gn = NEV - 1;
    const float* src = T + (size_t)gn*DIM + lj*16;
    #pragma unroll
    for (int q = 0; q < 4; ++q)
      *(float4*)(&Y[lr][lj*16 + q*4]) = *(const float4*)(src + q*4);
  }
  __syncthreads();
  int rq = tid >> 5, cq = tid & 31;
  float acc[4][4];
  #pragma unroll
  for (int u=0;u<4;++u){ acc[u][0]=0;acc[u][1]=0;acc[u][2]=0;acc[u][3]=0; }
  const float* Crow = WP + cq*4;
  #pragma unroll 4
  for (int k = 0; k < 128; ++k){
    float4 c = *(const float4*)(Crow + (size_t)k*128);
    #pragma unroll
    for (int u = 0; u < 4; ++u){
      float y = Y[rq*4 + u][k];
      acc[u][0] += y*c.x; acc[u][1] += y*c.y; acc[u][2] += y*c.z; acc[u][3] += y*c.w;
    }
  }
  float4 b1v = *(const float4*)(b1p + cq*4);
  #pragma unroll
  for (int u = 0; u < 4; ++u){
    int e = n0 + rq*4 + u;
    if (e < NEV){
      float Bv = Bs[e];
      ushort4 h;
      h.x = f2bf(acc[u][0] + Bv*b1v.x); h.y = f2bf(acc[u][1] + Bv*b1v.y);
      h.z = f2bf(acc[u][2] + Bv*b1v.z); h.w = f2bf(acc[u][3] + Bv*b1v.w);
      *(ushort4*)(Ye + (size_t)e*DIM + cq*4) = h;
    }
  }
}

// ---------------- R = [Av*X | X0] @ [C1;C3] + Av*bA + Wb  (LDS-free, direct frags) ----------------
__global__ __launch_bounds__(256) void gemm_pq(
        const float* __restrict__ X, const float* __restrict__ X0,
        const float* __restrict__ Wb, const float* __restrict__ ws,
        float* __restrict__ R){
  const float* Aa = ws + A_OFF;
  const float* bA = ws + BA_OFF;
  const unsigned short* Bpack = (const unsigned short*)(ws + BPACK_OFF);
  int t = threadIdx.x;
  int w = t >> 6, l = t & 63;
  int lr = l & 15, lg = l >> 4;
  int r0 = blockIdx.x * 64 + w * 16;      // wave's 16-row tile
  int ar = r0 + lr; if (ar >= NV) ar = NV - 1;
  float Ar = Aa[ar];
  const float* xrow  = X  + (size_t)ar*DIM + lg*8;
  const float* x0row = X0 + (size_t)ar*DIM + lg*8;
  f32x4 acc[8];
  #pragma unroll
  for (int ct = 0; ct < 8; ++ct) acc[ct] = (f32x4){0.f,0.f,0.f,0.f};
  #pragma unroll
  for (int ks = 0; ks < 8; ++ks){
    const float* src = (ks < 4) ? (xrow + ks*32) : (x0row + (ks-4)*32);
    float4 v0 = *(const float4*)(src);
    float4 v1 = *(const float4*)(src + 4);
    if (ks < 4){
      v0.x*=Ar; v0.y*=Ar; v0.z*=Ar; v0.w*=Ar;
      v1.x*=Ar; v1.y*=Ar; v1.z*=Ar; v1.w*=Ar;
    }
    bf16x8 af;
    af[0]=(short)f2bf(v0.x); af[1]=(short)f2bf(v0.y);
    af[2]=(short)f2bf(v0.z); af[3]=(short)f2bf(v0.w);
    af[4]=(short)f2bf(v1.x); af[5]=(short)f2bf(v1.y);
    af[6]=(short)f2bf(v1.z); af[7]=(short)f2bf(v1.w);
    const bf16x8* bp = (const bf16x8*)(Bpack) + (size_t)ks*8*64 + l;
    #pragma unroll
    for (int ct = 0; ct < 8; ++ct)
      acc[ct] = __builtin_amdgcn_mfma_f32_16x16x32_bf16(af, bp[ct*64], acc[ct], 0, 0, 0);
  }
  float Av_[4];
  #pragma unroll
  for (int r = 0; r < 4; ++r){
    int row = r0 + lg*4 + r;
    Av_[r] = (row < NV) ? Aa[row] : 0.f;
  }
  #pragma unroll
  for (int ct = 0; ct < 8; ++ct){
    int o = ct*16 + lr;
    float ba = bA[o], wb = Wb[o];
    #pragma unroll
    for (int r = 0; r < 4; ++r){
      int row = r0 + lg*4 + r;
      if (row < NV)
        R[(size_t)row*DIM + o] = acc[ct][r] + Av_[r]*ba + wb;
    }
  }
}

// ---------------- wave-per-vertex: out[v] += sum a*Ye[e]  (ushort2 gathers) ----------------
__global__ __launch_bounds__(256) void vertex_fused(
        const unsigned short* __restrict__ Ye, const int* __restrict__ offV,
        const int2* __restrict__ PV, float* __restrict__ out){
  int w = threadIdx.x >> 6, l = threadIdx.x & 63;
  int v = blockIdx.x*4 + w;
  int s0 = offV[v], s1 = offV[v+1];
  float acc0 = 0.f, acc1 = 0.f;
  int j = s0;
  for (; j + 8 <= s1; j += 8){
    int2 p[8];
    #pragma unroll
    for (int q = 0; q < 8; ++q) p[q] = PV[j + q];
    float lo[8], hi[8];
    #pragma unroll
    for (int q = 0; q < 8; ++q){
      int e = (p[q].x & 0x3FFF) << 7;
      unsigned yy = *(const unsigned*)(Ye + e + 2*l);
      lo[q] = bf2f((unsigned short)(yy & 0xFFFF));
      hi[q] = bf2f((unsigned short)(yy >> 16));
    }
    #pragma unroll
    for (int q = 0; q < 8; ++q){
      float a = __int_as_float(p[q].y);
      acc0 += a * lo[q]; acc1 += a * hi[q];
    }
  }
  for (; j < s1; ++j){
    int2 p = PV[j];
    int e = (p.x & 0x3FFF) << 7;
    unsigned yy = *(const unsigned*)(Ye + e + 2*l);
    float a = __int_as_float(p.y);
    acc0 += a * bf2f((unsigned short)(yy & 0xFFFF));
    acc1 += a * bf2f((unsigned short)(yy >> 16));
  }
  float* dst = out + (size_t)v*DIM + 2*l;
  float2 cur = *(float2*)dst;          // R already there; same thread, same address
  cur.x += acc0; cur.y += acc1;
  *(float2*)dst = cur;
}

extern "C" void kernel_launch(void* const* d_in, const int* in_sizes, int n_in,
                              void* d_out, int out_size, void* d_ws, size_t ws_size,
                              hipStream_t stream){
  const float* X    = (const float*)d_in[0];
  const int*  vertex= (const int*)  d_in[1];
  const int*  edges = (const int*)  d_in[2];
  const float* X0   = (const float*)d_in[3];
  const float* alpha= (const float*)d_in[4];
  const float* W1w  = (const float*)d_in[5];
  const float* W1b  = (const float*)d_in[6];
  const float* W2w  = (const float*)d_in[7];
  const float* W2b  = (const float*)d_in[8];
  const float* Ww   = (const float*)d_in[9];
  const float* Wb   = (const float*)d_in[10];
  float* out = (float*)d_out;
  float* ws  = (float*)d_ws;

  int* bcntE = (int*)(ws + BCNTE_OFF);
  int* bOffE = (int*)(ws + BOFFE_OFF);
  int* bcntV = (int*)(ws + BCNTV_OFF);
  int* bOffV = (int*)(ws + BOFFV_OFF);
  int* offE  = (int*)(ws + OFFE_OFF);
  int* bcurE = (int*)(ws + CURE_OFF);
  int* offV  = (int*)(ws + OFFV_OFF);
  int* bcurV = (int*)(ws + CURV_OFF);
  int2* PV   = (int2*)(ws + PV_OFF);
  int2* PE   = (int2*)(out + PE_OUT_FLOAT_OFF);
  int2* bounce = (int2*)(ws + T_OFF);
  unsigned short* Xbf = (unsigned short*)out;           // front 12.8 MB of d_out
  unsigned short* Ye  = (unsigned short*)(ws + XEBF_OFF);

  prep1        <<<389, 128, 0, stream>>>(W2w, W2b, Ww, ws);
  prep2        <<<129, 128, 0, stream>>>(W1w, W1b, ws);
  count_tobf16 <<<NCB + (NV*DIM/8 + 255)/256, 256, 0, stream>>>(vertex, edges, X,
                                                                bcntE, bcntV, Xbf);
  scan_buckets <<<1, 256, 0, stream>>>(bcntE, bcntV, bOffE, bOffV, bcurE, bcurV,
                                       offE, offV);
  fill_binned2 <<<(NNZV + CH2 - 1)/CH2, 256, 0, stream>>>(vertex, edges, alpha,
                                                          bcurE, bcurV, PE, PV);
  sort_bucket  <<<NBKE, 256, 0, stream>>>(PE, bOffE, offE, ws + B_OFF, bounce, 64,  16, NEV);
  sort_bucket  <<<NBKV, 256, 0, stream>>>(PV, bOffV, offV, ws + A_OFF, bounce, 256, 14, NV);
  edge_reduce  <<<NEV/4, 256, 0, stream>>>(Xbf, offE, PE, ws + T_OFF);
  gemm_ye      <<<(NEV + 31)/32, 256, 0, stream>>>(ws);
  gemm_pq      <<<(NV + 63)/64, 256, 0, stream>>>(X, X0, Wb, ws, out);
  vertex_fused <<<NV/4, 256, 0, stream>>>(Ye, offV, PV, out);
}

// Round 16
// 178.791 us; speedup vs baseline: 1.4362x; 1.0051x over previous
//
#include <hip/hip_runtime.h>

#define NV   50000
#define NEV  10000
#define NNZV 600000
#define DIM  128

#define NBKE 157    // edge buckets: e>>6  (64 keys each)
#define NBKV 196    // vertex buckets: v>>8 (256 keys each)
#define NCB  293    // count blocks (2048 items each)
#define CH2  2048   // fused fill chunk
#define SCAP 7680

// workspace layout (float offsets) — total 3,401,920 floats = 13.6 MB (proven)
#define BPACK_OFF 0        // 16384: bf16 256x128 packed [C1;C3] (32768 ushorts)
#define WP_OFF    24576    // 16384: W'' = W1^T @ C2, f32 [k][o]
#define BA_OFF    40960    // 256: bA[0..128), b1C2[128..256)
#define A_OFF     41216    // 50048: per-vertex alpha sum
#define B_OFF     91264    // 10048: per-edge alpha sum
#define T_OFF     101312   // 1280000: f32 T; also C2tmp during prep + int2 bounce
#define XEBF_OFF  1381312  // 640000 floats: bf16 Ye (1.28M ushort)
#define BCNTE_OFF 2021312  // int 256
#define BOFFE_OFF 2021568  // int 256
#define BCNTV_OFF 2021824  // int 256
#define BOFFV_OFF 2022080  // int 256
#define OFFE_OFF  2031328  // int 10016: exact-key CSR offsets (edges)
#define CURE_OFF  2041344  // int (bcurE uses first 157)
#define OFFV_OFF  2101376  // int 50016: exact-key CSR offsets (vertices)
#define CURV_OFF  2151392  // int (bcurV uses first 196)
#define PV_OFF    2201920  // int2 600000: (v<<14|e, alpha) grouped by vertex
// d_out timeline: Xbf (bf16 X, front 12.8MB) + PE pairs (int2 at float 3.2M) are
// written early, consumed by edge_reduce, then gemm_pq overwrites ALL of d_out
// with R rows; vertex_fused does wave-local RMW of its own row.
#define PE_OUT_FLOAT_OFF 3200000

typedef __attribute__((ext_vector_type(8))) short bf16x8;
typedef __attribute__((ext_vector_type(4))) float f32x4;

__device__ __forceinline__ unsigned short f2bf(float x){
  unsigned u = __float_as_uint(x);
  u += 0x7fffu + ((u >> 16) & 1u);     // round-to-nearest-even
  return (unsigned short)(u >> 16);
}
__device__ __forceinline__ float bf2f(unsigned short h){
  return __uint_as_float((unsigned)h << 16);
}

// ---------------- prep1: pack [C1;C3], C2tmp, bA; blocks 385-388 zero counts ----------------
__global__ __launch_bounds__(128) void prep1(
        const float* __restrict__ W2w, const float* __restrict__ W2b,
        const float* __restrict__ Ww, float* __restrict__ ws){
  int b = blockIdx.x, o = threadIdx.x;
  if (b < 256){
    float s;
    if (b < 128){            // C1[k=b][o] = 0.5*sum_m Ww[o][m]*W2w[m][b]
      float acc = 0.f;
      for (int m = 0; m < 128; ++m) acc += Ww[o*128 + m] * W2w[m*256 + b];
      s = 0.5f * acc;
    } else {                 // C3[k=b-128][o] = 0.5*Ww[o][b-128]
      s = 0.5f * Ww[o*128 + (b - 128)];
    }
    int ks = b >> 5, g = (b >> 3) & 3, j = b & 7;
    int ct = o >> 4, lo = o & 15;
    unsigned short* Bp = (unsigned short*)(ws + BPACK_OFF);
    Bp[((size_t)((ks*8 + ct)*64 + g*16 + lo))*8 + j] = f2bf(s);
  } else if (b < 384){       // C2tmp[m][o]
    int m = b - 256;
    float acc = 0.f;
    for (int j = 0; j < 128; ++j) acc += Ww[o*128 + j] * W2w[j*256 + 128 + m];
    ws[T_OFF + m*128 + o] = 0.5f * acc;
  } else if (b == 384){      // bA
    float acc = 0.f;
    for (int m = 0; m < 128; ++m) acc += Ww[o*128 + m] * W2b[m];
    ws[BA_OFF + o] = 0.5f * acc;
  } else {                   // zero the 1024-int bcnt/bOff block
    int* z = (int*)(ws + BCNTE_OFF);
    int base = (b - 385)*256;
    z[base + o] = 0; z[base + 128 + o] = 0;
  }
}

// ---------------- prep2: W'' = W1^T @ C2tmp; b1C2 ----------------
__global__ __launch_bounds__(128) void prep2(
        const float* __restrict__ W1w, const float* __restrict__ W1b,
        float* __restrict__ ws){
  int b = blockIdx.x, o = threadIdx.x;
  const float* C2t = ws + T_OFF;
  if (b < 128){
    float acc = 0.f;
    for (int m = 0; m < 128; ++m) acc += W1w[m*128 + b] * C2t[m*128 + o];
    ws[WP_OFF + b*128 + o] = acc;
  } else {
    float acc = 0.f;
    for (int m = 0; m < 128; ++m) acc += W1b[m] * C2t[m*128 + o];
    ws[BA_OFF + 128 + o] = acc;
  }
}

// ---------------- merged: bucket histogram (blocks <NCB) + X->bf16 (rest) ----------------
__global__ __launch_bounds__(256) void count_tobf16(
        const int* __restrict__ vertex, const int* __restrict__ edges,
        const float* __restrict__ X,
        int* __restrict__ bcntE, int* __restrict__ bcntV,
        unsigned short* __restrict__ Xbf){
  int b = blockIdx.x, t = threadIdx.x;
  __shared__ int hE[256], hV[256];
  if (b < NCB){
    hE[t] = 0; hV[t] = 0;
    __syncthreads();
    int i0 = b * 2048;
    #pragma unroll
    for (int r = 0; r < 8; ++r){
      int i = i0 + r*256 + t;
      if (i < NNZV){
        atomicAdd(&hE[edges[i]  >> 6], 1);
        atomicAdd(&hV[vertex[i] >> 8], 1);
      }
    }
    __syncthreads();
    if (hE[t]) atomicAdd(bcntE + t, hE[t]);
    if (hV[t]) atomicAdd(bcntV + t, hV[t]);
  } else {
    int i = (b - NCB)*256 + t;
    if (i < NV*DIM/8){
      float4 v0 = ((const float4*)X)[(size_t)i*2];
      float4 v1 = ((const float4*)X)[(size_t)i*2 + 1];
      ushort4 h0, h1;
      h0.x=f2bf(v0.x); h0.y=f2bf(v0.y); h0.z=f2bf(v0.z); h0.w=f2bf(v0.w);
      h1.x=f2bf(v1.x); h1.y=f2bf(v1.y); h1.z=f2bf(v1.z); h1.w=f2bf(v1.w);
      ((ushort4*)Xbf)[(size_t)i*2]     = h0;
      ((ushort4*)Xbf)[(size_t)i*2 + 1] = h1;
    }
  }
}

// ---------------- tiny: scan bucket counts, init cursors, set tail offs ----------------
__global__ __launch_bounds__(256) void scan_buckets(
        const int* __restrict__ bcntE, const int* __restrict__ bcntV,
        int* __restrict__ bOffE, int* __restrict__ bOffV,
        int* __restrict__ bcurE, int* __restrict__ bcurV,
        int* __restrict__ offE, int* __restrict__ offV){
  __shared__ int s[256];
  int t = threadIdx.x;
  int c = (t < NBKE) ? bcntE[t] : 0;
  s[t] = c; __syncthreads();
  for (int d = 1; d < 256; d <<= 1){
    int x = (t >= d) ? s[t-d] : 0;
    __syncthreads(); s[t] += x; __syncthreads();
  }
  if (t < NBKE){ bOffE[t] = s[t] - c; bcurE[t] = s[t] - c; }
  if (t == 0){ bOffE[NBKE] = NNZV; offE[NEV] = NNZV; }
  __syncthreads();
  int c2 = (t < NBKV) ? bcntV[t] : 0;
  s[t] = c2; __syncthreads();
  for (int d = 1; d < 256; d <<= 1){
    int x = (t >= d) ? s[t-d] : 0;
    __syncthreads(); s[t] += x; __syncthreads();
  }
  if (t < NBKV){ bOffV[t] = s[t] - c2; bcurV[t] = s[t] - c2; }
  if (t == 0){ bOffV[NBKV] = NNZV; offV[NV] = NNZV; }
}

// ---------------- fused binning: one pass produces PE and PV ----------------
__global__ __launch_bounds__(256) void fill_binned2(
        const int* __restrict__ vertex, const int* __restrict__ edges,
        const float* __restrict__ alpha,
        int* __restrict__ bcurE, int* __restrict__ bcurV,
        int2* __restrict__ PE, int2* __restrict__ PV){
  __shared__ int histE[256], lofsE[256], gbaseE[256], posE[256];
  __shared__ int histV[256], lofsV[256], gbaseV[256], posV[256];
  __shared__ int ss[256];
  __shared__ int2 stgE[CH2], stgV[CH2];
  int t = threadIdx.x;
  int i0 = blockIdx.x * CH2;
  histE[t] = 0; histV[t] = 0;
  __syncthreads();
  int pkE[8], pkV[8], pa[8];
  #pragma unroll
  for (int r = 0; r < 8; ++r){
    int i = i0 + r*256 + t;
    int pe = -1, pv = -1, ab = 0;
    if (i < NNZV){
      int v = vertex[i], e = edges[i];
      ab = __float_as_int(alpha[i]);
      pe = (e << 16) | v;              // pe>>22 == e>>6
      pv = (v << 14) | e;              // pv>>22 == v>>8
      atomicAdd(&histE[pe >> 22], 1);
      atomicAdd(&histV[pv >> 22], 1);
    }
    pkE[r] = pe; pkV[r] = pv; pa[r] = ab;
  }
  __syncthreads();
  int cE = histE[t];
  ss[t] = cE; __syncthreads();
  for (int d = 1; d < 256; d <<= 1){
    int x = (t >= d) ? ss[t-d] : 0;
    __syncthreads(); ss[t] += x; __syncthreads();
  }
  lofsE[t] = ss[t] - cE; posE[t] = ss[t] - cE;
  __syncthreads();
  int cV = histV[t];
  ss[t] = cV; __syncthreads();
  for (int d = 1; d < 256; d <<= 1){
    int x = (t >= d) ? ss[t-d] : 0;
    __syncthreads(); ss[t] += x; __syncthreads();
  }
  lofsV[t] = ss[t] - cV; posV[t] = ss[t] - cV;
  __syncthreads();
  #pragma unroll
  for (int r = 0; r < 8; ++r){
    if (pkE[r] != -1){
      int p = atomicAdd(&posE[pkE[r] >> 22], 1);
      stgE[p] = make_int2(pkE[r], pa[r]);
      int q = atomicAdd(&posV[pkV[r] >> 22], 1);
      stgV[q] = make_int2(pkV[r], pa[r]);
    }
  }
  __syncthreads();
  {
    int cnt = histE[t];
    gbaseE[t] = cnt ? atomicAdd(&bcurE[t], cnt) : 0;
    int cnt2 = histV[t];
    gbaseV[t] = cnt2 ? atomicAdd(&bcurV[t], cnt2) : 0;
  }
  __syncthreads();
  int total = min(CH2, NNZV - i0);
  for (int s = t; s < total; s += 256){
    int lo = 0, hi = NBKE - 1;
    while (lo < hi){ int mid = (lo + hi + 1) >> 1; if (lofsE[mid] <= s) lo = mid; else hi = mid - 1; }
    PE[gbaseE[lo] + (s - lofsE[lo])] = stgE[s];
    lo = 0; hi = NBKV - 1;
    while (lo < hi){ int mid = (lo + hi + 1) >> 1; if (lofsV[mid] <= s) lo = mid; else hi = mid - 1; }
    PV[gbaseV[lo] + (s - lofsV[lo])] = stgV[s];
  }
}

// ---------------- in-bucket counting sort + exact-key off + alpha sums ----------------
__global__ __launch_bounds__(256) void sort_bucket(
        int2* __restrict__ pairs, const int* __restrict__ bOff,
        int* __restrict__ off, float* __restrict__ sums,
        int2* __restrict__ bounce, int kpb, int shift, int nkeys){
  int b = blockIdx.x, t = threadIdx.x;
  int k0 = b * kpb;
  int r0 = bOff[b], r1 = bOff[b+1];
  int m = r1 - r0;
  __shared__ int hist[256], rnk[256], ssc[256];
  __shared__ int2 srt[SCAP];
  for (int q = t; q < kpb; q += 256) hist[q] = 0;
  __syncthreads();
  int px[30], py[30];
  #pragma unroll
  for (int r = 0; r < 30; ++r){
    int s = r*256 + t;
    int x = -1, y = 0;
    if (s < m && m <= SCAP){
      int2 p = pairs[r0 + s];
      x = p.x; y = p.y;
      atomicAdd(&hist[(x >> shift) - k0], 1);
    }
    px[r] = x; py[r] = y;
  }
  if (m > SCAP){   // statistically never taken; correct fallback via global bounce
    for (int s = t; s < m; s += 256){
      int2 p = pairs[r0 + s];
      bounce[s] = p;
      atomicAdd(&hist[(p.x >> shift) - k0], 1);
    }
  }
  __syncthreads();
  int c = (t < kpb) ? hist[t] : 0;
  ssc[t] = c; __syncthreads();
  for (int d = 1; d < 256; d <<= 1){
    int x = (t >= d) ? ssc[t-d] : 0;
    __syncthreads(); ssc[t] += x; __syncthreads();
  }
  if (t < kpb){
    rnk[t] = ssc[t] - c;
    int k = k0 + t;
    if (k < nkeys) off[k] = r0 + ssc[t] - c;
  }
  __syncthreads();
  if (m <= SCAP){
    #pragma unroll
    for (int r = 0; r < 30; ++r){
      if (px[r] >= 0){
        int p = atomicAdd(&rnk[(px[r] >> shift) - k0], 1);
        srt[p] = make_int2(px[r], py[r]);
      }
    }
    __syncthreads();
    for (int s = t; s < m; s += 256) pairs[r0 + s] = srt[s];
    if (t < kpb){
      int k = k0 + t;
      if (k < nkeys){
        float sa = 0.f;
        int s0 = ssc[t] - hist[t], s1 = ssc[t];
        for (int s = s0; s < s1; ++s) sa += __int_as_float(srt[s].y);
        sums[k] = sa;
      }
    }
  } else {
    __syncthreads();
    for (int s = t; s < m; s += 256){
      int2 p = bounce[s];
      int q = atomicAdd(&rnk[(p.x >> shift) - k0], 1);
      pairs[r0 + q] = p;
    }
    __syncthreads();
    if (t < kpb){
      int k = k0 + t;
      if (k < nkeys){
        float sa = 0.f;
        int s0 = ssc[t] - hist[t], s1 = ssc[t];
        for (int s = s0; s < s1; ++s) sa += __int_as_float(pairs[r0 + s].y);
        sums[k] = sa;
      }
    }
  }
}

// ---------------- wave-per-edge reduce: T[e] = sum a*Xbf[v]  (ushort2 gathers) ----------------
__global__ __launch_bounds__(256) void edge_reduce(
        const unsigned short* __restrict__ Xbf, const int* __restrict__ offE,
        const int2* __restrict__ PE, float* __restrict__ T){
  int w = threadIdx.x >> 6, l = threadIdx.x & 63;
  int e = blockIdx.x*4 + w;
  int s0 = offE[e], s1 = offE[e+1];
  float acc0 = 0.f, acc1 = 0.f;
  int j = s0;
  for (; j + 8 <= s1; j += 8){
    int2 p[8];
    #pragma unroll
    for (int q = 0; q < 8; ++q) p[q] = PE[j + q];
    float lo[8], hi[8];
    #pragma unroll
    for (int q = 0; q < 8; ++q){
      int v = (p[q].x & 0xFFFF) << 7;
      unsigned xx = *(const unsigned*)(Xbf + v + 2*l);
      lo[q] = bf2f((unsigned short)(xx & 0xFFFF));
      hi[q] = bf2f((unsigned short)(xx >> 16));
    }
    #pragma unroll
    for (int q = 0; q < 8; ++q){
      float a = __int_as_float(p[q].y);
      acc0 += a * lo[q]; acc1 += a * hi[q];
    }
  }
  for (; j < s1; ++j){
    int2 p = PE[j];
    int v = (p.x & 0xFFFF) << 7;
    unsigned xx = *(const unsigned*)(Xbf + v + 2*l);
    float a = __int_as_float(p.y);
    acc0 += a * bf2f((unsigned short)(xx & 0xFFFF));
    acc1 += a * bf2f((unsigned short)(xx >> 16));
  }
  float2 o2; o2.x = acc0; o2.y = acc1;
  *(float2*)(T + (size_t)e*DIM + 2*l) = o2;
}

// ---------------- Ye = T @ W'' + B*b1C2  (writes bf16 XEBF) ----------------
__global__ __launch_bounds__(256) void gemm_ye(float* __restrict__ ws){
  __shared__ float Y[32][136];
  const float* T   = ws + T_OFF;
  const float* WP  = ws + WP_OFF;
  const float* Bs  = ws + B_OFF;
  const float* b1p = ws + BA_OFF + 128;
  unsigned short* Ye = (unsigned short*)(ws + XEBF_OFF);
  int n0 = blockIdx.x * 32;
  int tid = threadIdx.x;
  {
    int lr = tid >> 3, lj = tid & 7;
    int gn = n0 + lr; if (gn >= NEV) gn = NEV - 1;
    const float* src = T + (size_t)gn*DIM + lj*16;
    #pragma unroll
    for (int q = 0; q < 4; ++q)
      *(float4*)(&Y[lr][lj*16 + q*4]) = *(const float4*)(src + q*4);
  }
  __syncthreads();
  int rq = tid >> 5, cq = tid & 31;
  float acc[4][4];
  #pragma unroll
  for (int u=0;u<4;++u){ acc[u][0]=0;acc[u][1]=0;acc[u][2]=0;acc[u][3]=0; }
  const float* Crow = WP + cq*4;
  #pragma unroll 4
  for (int k = 0; k < 128; ++k){
    float4 c = *(const float4*)(Crow + (size_t)k*128);
    #pragma unroll
    for (int u = 0; u < 4; ++u){
      float y = Y[rq*4 + u][k];
      acc[u][0] += y*c.x; acc[u][1] += y*c.y; acc[u][2] += y*c.z; acc[u][3] += y*c.w;
    }
  }
  float4 b1v = *(const float4*)(b1p + cq*4);
  #pragma unroll
  for (int u = 0; u < 4; ++u){
    int e = n0 + rq*4 + u;
    if (e < NEV){
      float Bv = Bs[e];
      ushort4 h;
      h.x = f2bf(acc[u][0] + Bv*b1v.x); h.y = f2bf(acc[u][1] + Bv*b1v.y);
      h.z = f2bf(acc[u][2] + Bv*b1v.z); h.w = f2bf(acc[u][3] + Bv*b1v.w);
      *(ushort4*)(Ye + (size_t)e*DIM + cq*4) = h;
    }
  }
}

// ---------------- R = [Av*X | X0] @ [C1;C3] + Av*bA + Wb  (LDS-free, direct frags) ----------------
__global__ __launch_bounds__(256) void gemm_pq(
        const float* __restrict__ X, const float* __restrict__ X0,
        const float* __restrict__ Wb, const float* __restrict__ ws,
        float* __restrict__ R){
  const float* Aa = ws + A_OFF;
  const float* bA = ws + BA_OFF;
  const unsigned short* Bpack = (const unsigned short*)(ws + BPACK_OFF);
  int t = threadIdx.x;
  int w = t >> 6, l = t & 63;
  int lr = l & 15, lg = l >> 4;
  int r0 = blockIdx.x * 64 + w * 16;      // wave's 16-row tile
  int ar = r0 + lr; if (ar >= NV) ar = NV - 1;
  float Ar = Aa[ar];
  const float* xrow  = X  + (size_t)ar*DIM + lg*8;
  const float* x0row = X0 + (size_t)ar*DIM + lg*8;
  f32x4 acc[8];
  #pragma unroll
  for (int ct = 0; ct < 8; ++ct) acc[ct] = (f32x4){0.f,0.f,0.f,0.f};
  #pragma unroll
  for (int ks = 0; ks < 8; ++ks){
    const float* src = (ks < 4) ? (xrow + ks*32) : (x0row + (ks-4)*32);
    float4 v0 = *(const float4*)(src);
    float4 v1 = *(const float4*)(src + 4);
    if (ks < 4){
      v0.x*=Ar; v0.y*=Ar; v0.z*=Ar; v0.w*=Ar;
      v1.x*=Ar; v1.y*=Ar; v1.z*=Ar; v1.w*=Ar;
    }
    bf16x8 af;
    af[0]=(short)f2bf(v0.x); af[1]=(short)f2bf(v0.y);
    af[2]=(short)f2bf(v0.z); af[3]=(short)f2bf(v0.w);
    af[4]=(short)f2bf(v1.x); af[5]=(short)f2bf(v1.y);
    af[6]=(short)f2bf(v1.z); af[7]=(short)f2bf(v1.w);
    const bf16x8* bp = (const bf16x8*)(Bpack) + (size_t)ks*8*64 + l;
    #pragma unroll
    for (int ct = 0; ct < 8; ++ct)
      acc[ct] = __builtin_amdgcn_mfma_f32_16x16x32_bf16(af, bp[ct*64], acc[ct], 0, 0, 0);
  }
  float Av_[4];
  #pragma unroll
  for (int r = 0; r < 4; ++r){
    int row = r0 + lg*4 + r;
    Av_[r] = (row < NV) ? Aa[row] : 0.f;
  }
  #pragma unroll
  for (int ct = 0; ct < 8; ++ct){
    int o = ct*16 + lr;
    float ba = bA[o], wb = Wb[o];
    #pragma unroll
    for (int r = 0; r < 4; ++r){
      int row = r0 + lg*4 + r;
      if (row < NV)
        R[(size_t)row*DIM + o] = acc[ct][r] + Av_[r]*ba + wb;
    }
  }
}

// ---------------- wave-per-vertex: out[v] += sum a*Ye[e]  (ushort2 gathers) ----------------
__global__ __launch_bounds__(256) void vertex_fused(
        const unsigned short* __restrict__ Ye, const int* __restrict__ offV,
        const int2* __restrict__ PV, float* __restrict__ out){
  int w = threadIdx.x >> 6, l = threadIdx.x & 63;
  int v = blockIdx.x*4 + w;
  int s0 = offV[v], s1 = offV[v+1];
  float acc0 = 0.f, acc1 = 0.f;
  int j = s0;
  for (; j + 8 <= s1; j += 8){
    int2 p[8];
    #pragma unroll
    for (int q = 0; q < 8; ++q) p[q] = PV[j + q];
    float lo[8], hi[8];
    #pragma unroll
    for (int q = 0; q < 8; ++q){
      int e = (p[q].x & 0x3FFF) << 7;
      unsigned yy = *(const unsigned*)(Ye + e + 2*l);
      lo[q] = bf2f((unsigned short)(yy & 0xFFFF));
      hi[q] = bf2f((unsigned short)(yy >> 16));
    }
    #pragma unroll
    for (int q = 0; q < 8; ++q){
      float a = __int_as_float(p[q].y);
      acc0 += a * lo[q]; acc1 += a * hi[q];
    }
  }
  for (; j < s1; ++j){
    int2 p = PV[j];
    int e = (p.x & 0x3FFF) << 7;
    unsigned yy = *(const unsigned*)(Ye + e + 2*l);
    float a = __int_as_float(p.y);
    acc0 += a * bf2f((unsigned short)(yy & 0xFFFF));
    acc1 += a * bf2f((unsigned short)(yy >> 16));
  }
  float* dst = out + (size_t)v*DIM + 2*l;
  float2 cur = *(float2*)dst;          // R already there; same thread, same address
  cur.x += acc0; cur.y += acc1;
  *(float2*)dst = cur;
}

extern "C" void kernel_launch(void* const* d_in, const int* in_sizes, int n_in,
                              void* d_out, int out_size, void* d_ws, size_t ws_size,
                              hipStream_t stream){
  const float* X    = (const float*)d_in[0];
  const int*  vertex= (const int*)  d_in[1];
  const int*  edges = (const int*)  d_in[2];
  const float* X0   = (const float*)d_in[3];
  const float* alpha= (const float*)d_in[4];
  const float* W1w  = (const float*)d_in[5];
  const float* W1b  = (const float*)d_in[6];
  const float* W2w  = (const float*)d_in[7];
  const float* W2b  = (const float*)d_in[8];
  const float* Ww   = (const float*)d_in[9];
  const float* Wb   = (const float*)d_in[10];
  float* out = (float*)d_out;
  float* ws  = (float*)d_ws;

  int* bcntE = (int*)(ws + BCNTE_OFF);
  int* bOffE = (int*)(ws + BOFFE_OFF);
  int* bcntV = (int*)(ws + BCNTV_OFF);
  int* bOffV = (int*)(ws + BOFFV_OFF);
  int* offE  = (int*)(ws + OFFE_OFF);
  int* bcurE = (int*)(ws + CURE_OFF);
  int* offV  = (int*)(ws + OFFV_OFF);
  int* bcurV = (int*)(ws + CURV_OFF);
  int2* PV   = (int2*)(ws + PV_OFF);
  int2* PE   = (int2*)(out + PE_OUT_FLOAT_OFF);
  int2* bounce = (int2*)(ws + T_OFF);
  unsigned short* Xbf = (unsigned short*)out;           // front 12.8 MB of d_out
  unsigned short* Ye  = (unsigned short*)(ws + XEBF_OFF);

  prep1        <<<389, 128, 0, stream>>>(W2w, W2b, Ww, ws);
  prep2        <<<129, 128, 0, stream>>>(W1w, W1b, ws);
  count_tobf16 <<<NCB + (NV*DIM/8 + 255)/256, 256, 0, stream>>>(vertex, edges, X,
                                                                bcntE, bcntV, Xbf);
  scan_buckets <<<1, 256, 0, stream>>>(bcntE, bcntV, bOffE, bOffV, bcurE, bcurV,
                                       offE, offV);
  fill_binned2 <<<(NNZV + CH2 - 1)/CH2, 256, 0, stream>>>(vertex, edges, alpha,
                                                          bcurE, bcurV, PE, PV);
  sort_bucket  <<<NBKE, 256, 0, stream>>>(PE, bOffE, offE, ws + B_OFF, bounce, 64,  16, NEV);
  sort_bucket  <<<NBKV, 256, 0, stream>>>(PV, bOffV, offV, ws + A_OFF, bounce, 256, 14, NV);
  edge_reduce  <<<NEV/4, 256, 0, stream>>>(Xbf, offE, PE, ws + T_OFF);
  gemm_ye      <<<(NEV + 31)/32, 256, 0, stream>>>(ws);
  gemm_pq      <<<(NV + 63)/64, 256, 0, stream>>>(X, X0, Wb, ws, out);
  vertex_fused <<<NV/4, 256, 0, stream>>>(Ye, offV, PV, out);
}